// Round 5
// baseline (317.716 us; speedup 1.0000x reference)
//
#include <hip/hip_runtime.h>
#include <stdint.h>

#define DEV __device__ __forceinline__

typedef uint16_t u16;
typedef __attribute__((ext_vector_type(8))) short short8;
typedef __attribute__((ext_vector_type(4))) float f32x4;
typedef __attribute__((ext_vector_type(8))) __bf16 bf16x8;
typedef __attribute__((ext_vector_type(4))) int int4v;
typedef __attribute__((ext_vector_type(2))) unsigned int u32x2;

static constexpr int Bn = 4, Sn = 2048, Dn = 768, Hn = 12, DFFn = 3072;
static constexpr int BS = Bn * Sn;   // 8192 tokens
static constexpr float EPS = 1e-6f;
static constexpr float C1 = 0.18033688011112042f;   // 0.125 * log2(e)
static constexpr float SHIFT = 11.541560327111707f; // 8 * log2(e)

DEV u16 f2bf(float f) {
  union { float f; uint32_t u; } cv; cv.f = f;
  uint32_t u = cv.u;
  u += 0x7FFFu + ((u >> 16) & 1u);   // round-to-nearest-even
  return (u16)(u >> 16);
}

DEV uint32_t pk_bf16(float a, float b) {
  union { __bf16 h[2]; uint32_t u; } cv;
  cv.h[0] = (__bf16)a; cv.h[1] = (__bf16)b;
  return cv.u;
}

DEV float exp2_raw(float x) {
  float r;
  asm("v_exp_f32 %0, %1" : "=v"(r) : "v"(x));
  return r;
}

DEV f32x4 mfma16(short8 a, short8 b, f32x4 c) {
  return __builtin_amdgcn_mfma_f32_16x16x32_bf16(
      __builtin_bit_cast(bf16x8, a), __builtin_bit_cast(bf16x8, b), c, 0, 0, 0);
}

DEV void glds16(const void* g, void* l) {
  __builtin_amdgcn_global_load_lds(
      (const __attribute__((address_space(1))) void*)g,
      (__attribute__((address_space(3))) void*)l, 16, 0, 0);
}

DEV void barf() {
  asm volatile("" ::: "memory");
  __builtin_amdgcn_s_barrier();
  asm volatile("" ::: "memory");
}
#define WAITV(n) asm volatile("s_waitcnt vmcnt(" #n ")" ::: "memory")

// inverse of slot u = (r*4 + s) ^ (r&7); valid for r < 256
DEV void inv_swz(int u, int& r, int& s) {
  r = ((u >> 2) & 0x1FE) | (((u >> 2) ^ (u >> 4)) & 1);
  s = ((u ^ (u >> 2) ^ (u >> 4)) & 1) | ((u ^ (u >> 2)) & 2);
}

// ---------------- converts / transposes ----------------

__global__ void cvt_x_kernel(const float* __restrict__ in, u16* __restrict__ out) {
  size_t i = (size_t)blockIdx.x * 256 + threadIdx.x;
  const f32x4* p = (const f32x4*)in + i * 2;
  f32x4 a = p[0], b = p[1];
  short8 o;
  o[0] = (short)f2bf(a[0]); o[1] = (short)f2bf(a[1]);
  o[2] = (short)f2bf(a[2]); o[3] = (short)f2bf(a[3]);
  o[4] = (short)f2bf(b[0]); o[5] = (short)f2bf(b[1]);
  o[6] = (short)f2bf(b[2]); o[7] = (short)f2bf(b[3]);
  *(short8*)(out + i * 8) = o;
}

// w[K][N] fp32 -> out[N][K] bf16 (optionally scaled)
__global__ void wtrans_kernel(const float* __restrict__ w, u16* __restrict__ out,
                              int K, int N, float scale) {
  __shared__ float T[32][33];
  int tx = threadIdx.x, ty = threadIdx.y;
  int n0 = blockIdx.x * 32, k0 = blockIdx.y * 32;
#pragma unroll
  for (int i = 0; i < 4; ++i)
    T[ty + 8 * i][tx] = w[(size_t)(k0 + ty + 8 * i) * N + n0 + tx];
  __syncthreads();
#pragma unroll
  for (int i = 0; i < 4; ++i)
    out[(size_t)(n0 + ty + 8 * i) * K + k0 + tx] = f2bf(T[tx][ty + 8 * i] * scale);
}

// qkv[token][2304], V section -> vt[bh][dk=64][S]
__global__ void vtrans_kernel(const u16* __restrict__ qkv, u16* __restrict__ vt) {
  __shared__ u16 T[64][72];
  const int tid = threadIdx.x;
  const int bh = blockIdx.y, b = bh / Hn, h = bh % Hn;
  const int s0 = blockIdx.x * 64;
  {
    int sl = tid >> 2, d0 = (tid & 3) * 16;
    const u16* src = qkv + (size_t)(b * Sn + s0 + sl) * 2304 + 1536 + h * 64 + d0;
    short8 v0 = *(const short8*)src;
    short8 v1 = *(const short8*)(src + 8);
    *(short8*)&T[sl][d0] = v0;
    *(short8*)&T[sl][d0 + 8] = v1;
  }
  __syncthreads();
  {
    int dk = tid >> 2, sl0 = (tid & 3) * 16;
    short8 o0, o1;
#pragma unroll
    for (int j = 0; j < 8; ++j) {
      o0[j] = (short)T[sl0 + j][dk];
      o1[j] = (short)T[sl0 + 8 + j][dk];
    }
    u16* dst = vt + (size_t)(bh * 64 + dk) * Sn + s0 + sl0;
    *(short8*)dst = o0;
    *(short8*)(dst + 8) = o1;
  }
}

// ============ GEMM BMx128, BK=32, per-wave 64x64, 1 barrier/tile ============
// C[M][N] = A[M][K] * Bt[N][K]^T.  XCD-aware block decode: y-panels
// round-robin across the 8 XCDs so blocks sharing an A-panel share an L2.

template<int BM, bool OUT_BF16, bool RELU, bool HAS_BIAS>
__global__ __launch_bounds__(BM * 2, 4)
void gemm_kernel(const u16* __restrict__ A, const u16* __restrict__ Bt,
                 const float* __restrict__ bias, void* __restrict__ Cout,
                 int N, int K, int gx) {
  constexpr int ABYTES = BM * 64;          // A bytes per buffer (BM x 32 bf16)
  constexpr int BUFSZ = ABYTES + 8192;     // + B (128 x 32 bf16)
  __shared__ char lds[2 * BUFSZ];
  const int tid = threadIdx.x;
  const int wave = tid >> 6, lane = tid & 63;
  const int lr = lane & 15, lg = lane >> 4;
  const int wr = wave >> 1, wc = wave & 1;

  const int kk = blockIdx.x >> 3, xcd = blockIdx.x & 7;
  const int row0 = (xcd + 8 * (kk / gx)) * BM, col0 = (kk % gx) * 128;

  size_t aofs[2], bofs[2];
#pragma unroll
  for (int i = 0; i < 2; ++i) {
    int r, s;
    inv_swz(tid + i * (BM * 2), r, s);
    aofs[i] = (size_t)(row0 + r) * K + s * 8;
  }
  {
    int r, s;
    inv_swz(tid, r, s);
    bofs[0] = (size_t)(col0 + r) * K + s * 8;
    if (BM == 128) {
      inv_swz(tid + 256, r, s);
      bofs[1] = (size_t)(col0 + r) * K + s * 8;
    }
  }
  const int aD0 = wave * 1024, aD1 = BM * 32 + wave * 1024;

  int aB[4], bB[4];
#pragma unroll
  for (int mi = 0; mi < 4; ++mi) {
    int row = wr * 64 + mi * 16 + lr;
    aB[mi] = ((row << 6) | (lg << 4)) ^ ((row & 7) << 4);
  }
#pragma unroll
  for (int nj = 0; nj < 4; ++nj) {
    int row = wc * 64 + nj * 16 + lr;
    bB[nj] = ((row << 6) | (lg << 4)) ^ ((row & 7) << 4);
  }

  f32x4 acc[4][4];
#pragma unroll
  for (int i = 0; i < 4; ++i)
#pragma unroll
    for (int j = 0; j < 4; ++j) acc[i][j] = (f32x4){0.f, 0.f, 0.f, 0.f};

  const int NT = K >> 5;
  auto stage = [&](char* buf, int kb) {
    glds16(A + aofs[0] + kb, buf + aD0);
    glds16(A + aofs[1] + kb, buf + aD1);
    glds16(Bt + bofs[0] + kb, buf + ABYTES + wave * 1024);
    if (BM == 128)
      glds16(Bt + bofs[1] + kb, buf + ABYTES + 4096 + wave * 1024);
  };

  stage(lds, 0);
  WAITV(0);
  barf();
  int cur = 0;
  for (int t = 0; t < NT; ++t) {
    char* cb = lds + cur * BUFSZ;
    if (t + 1 < NT) stage(lds + (cur ^ 1) * BUFSZ, (t + 1) * 32);
    short8 a_[4], b_[4];
#pragma unroll
    for (int mi = 0; mi < 4; ++mi)
      a_[mi] = *(const short8*)(cb + aB[mi]);
#pragma unroll
    for (int nj = 0; nj < 4; ++nj)
      b_[nj] = *(const short8*)(cb + ABYTES + bB[nj]);
    __builtin_amdgcn_s_setprio(1);
#pragma unroll
    for (int mi = 0; mi < 4; ++mi)
#pragma unroll
      for (int nj = 0; nj < 4; ++nj)
        acc[mi][nj] = mfma16(a_[mi], b_[nj], acc[mi][nj]);
    __builtin_amdgcn_s_setprio(0);
    WAITV(0);
    barf();
    cur ^= 1;
  }

#pragma unroll
  for (int mi = 0; mi < 4; ++mi) {
    int row = row0 + wr * 64 + mi * 16 + lg * 4;
#pragma unroll
    for (int nj = 0; nj < 4; ++nj) {
      int col = col0 + wc * 64 + nj * 16 + lr;
      float bv = HAS_BIAS ? bias[col] : 0.f;
#pragma unroll
      for (int r = 0; r < 4; ++r) {
        float v = acc[mi][nj][r] + bv;
        if (RELU) v = fmaxf(v, 0.f);
        size_t o = (size_t)(row + r) * N + col;
        if (OUT_BF16) ((u16*)Cout)[o] = f2bf(v);
        else ((float*)Cout)[o] = v;
      }
    }
  }
}

// ---------------- flash attention v5 ----------------
// 128 q-rows/block, static-shift softmax (scale folded into wq, shift into
// QK accumulator init), K/V fragments hoisted out of the q-set loop.

__global__ __launch_bounds__(256, 3)
void attn_kernel(const u16* __restrict__ qkv, const u16* __restrict__ vt,
                 const int* __restrict__ mask, u16* __restrict__ ctx) {
  __shared__ u16 kbuf[2][4096];
  __shared__ u16 vbuf[2][4096];
  __shared__ u16 pbuf[4][2][1024];

  const int tid = threadIdx.x;
  const int wave = tid >> 6, lane = tid & 63;
  const int lr = lane & 15, lg = lane >> 4;

  const int lin = blockIdx.x;
  const int logical = (lin & 7) * 96 + (lin >> 3);
  const int qt = logical & 15;
  const int bh = logical >> 4;
  const int b = bh / Hn, h = bh % Hn;

  int ok;
  {
    const int4v* ms = (const int4v*)(mask + b * Sn);
    int4v m0 = ms[tid * 2], m1 = ms[tid * 2 + 1];
    ok = m0[0] && m0[1] && m0[2] && m0[3] && m1[0] && m1[1] && m1[2] && m1[3];
  }
  const bool allones = (__syncthreads_and(ok) != 0);

  const int cu = (lane & 7) ^ (lane >> 3);
  const int r0 = wave * 16 + (lane >> 3);
  const u16* kg0 = qkv + (size_t)(b * Sn + r0) * 2304 + 768 + h * 64 + cu * 8;
  const u16* vg0 = vt + (size_t)(bh * 64 + r0) * Sn + cu * 8;
  u16* kd = &kbuf[0][0] + wave * 1024;
  u16* vd = &vbuf[0][0] + wave * 1024;

  const size_t qrowA = (size_t)(b * Sn + qt * 128 + wave * 16 + lr) * 2304 + h * 64 + lg * 8;
  short8 qa0 = *(const short8*)(qkv + qrowA);
  short8 qa1 = *(const short8*)(qkv + qrowA + 32);
  const size_t qrowB = qrowA + (size_t)64 * 2304;
  short8 qb0 = *(const short8*)(qkv + qrowB);
  short8 qb1 = *(const short8*)(qkv + qrowB + 32);

  const int rlo = (lg ^ (lr & 7)) << 4;
  const int rhi = ((4 + lg) ^ (lr & 7)) << 4;
  const int rowb = lr * 128;

  f32x4 caccA[4], caccB[4];
#pragma unroll
  for (int i = 0; i < 4; ++i) {
    caccA[i] = (f32x4){0.f, 0.f, 0.f, 0.f};
    caccB[i] = (f32x4){0.f, 0.f, 0.f, 0.f};
  }
  float lsA = 0.f, lsB = 0.f;

  u16* pwA = &pbuf[wave][0][0];
  u16* pwB = &pbuf[wave][1][0];
  const int pwr = (lg >> 1), pwo = 8 * (lg & 1);

  auto stage = [&](int bf, int c) {
    const u16* kg = kg0 + (size_t)c * 64 * 2304;
    const u16* vg = vg0 + c * 64;
    glds16(kg,            kd + bf * 4096);
    glds16(kg + 8 * 2304, kd + bf * 4096 + 512);
    glds16(vg,            vd + bf * 4096);
    glds16(vg + 8 * Sn,   vd + bf * 4096 + 512);
  };

  stage(0, 0);
  __syncthreads();
  int cur = 0;
  for (int c = 0; c < 32; ++c) {
    if (c + 1 < 32) stage(cur ^ 1, c + 1);
    const char* kb = (const char*)&kbuf[cur][0];
    const char* vb = (const char*)&vbuf[cur][0];

    // hoisted K and V fragments (shared by both q-sets)
    short8 kf[8], vf[8];
#pragma unroll
    for (int f = 0; f < 4; ++f) {
      kf[2 * f]     = *(const short8*)(kb + f * 2048 + rowb + rlo);
      kf[2 * f + 1] = *(const short8*)(kb + f * 2048 + rowb + rhi);
      vf[2 * f]     = *(const short8*)(vb + f * 2048 + rowb + rlo);
      vf[2 * f + 1] = *(const short8*)(vb + f * 2048 + rowb + rhi);
    }

    int4v mk[4];
    if (!allones) {
      const int4v* mp = (const int4v*)(mask + b * Sn + c * 64 + lg * 4);
#pragma unroll
      for (int f = 0; f < 4; ++f) mk[f] = mp[f * 4];
    }

#pragma unroll
    for (int set = 0; set < 2; ++set) {
      short8 q0 = set ? qb0 : qa0;
      short8 q1 = set ? qb1 : qa1;
      u16* pw = set ? pwB : pwA;
      f32x4* cacc = set ? caccB : caccA;
      float ls = 0.f;

      f32x4 sc[4];
#pragma unroll
      for (int f = 0; f < 4; ++f) {
        f32x4 z = (f32x4){-SHIFT, -SHIFT, -SHIFT, -SHIFT};
        z = mfma16(kf[2 * f], q0, z);
        z = mfma16(kf[2 * f + 1], q1, z);
        sc[f] = z;
      }
      if (!allones) {
#pragma unroll
        for (int f = 0; f < 4; ++f)
#pragma unroll
          for (int r = 0; r < 4; ++r)
            sc[f][r] = mk[f][r] ? sc[f][r] : -1.0e5f;
      }
#pragma unroll
      for (int f = 0; f < 4; ++f) {
#pragma unroll
        for (int r = 0; r < 4; ++r) {
          float p = exp2_raw(sc[f][r]);
          sc[f][r] = p;
          ls += p;
        }
      }
      if (set) lsB += ls; else lsA += ls;

#pragma unroll
      for (int f = 0; f < 4; ++f) {
        u32x2 w;
        w[0] = pk_bf16(sc[f][0], sc[f][1]);
        w[1] = pk_bf16(sc[f][2], sc[f][3]);
        *(u32x2*)((char*)pw + rowb + (((2 * f + pwr) ^ (lr & 7)) << 4) + pwo) = w;
      }
      short8 pf0 = *(const short8*)((const char*)pw + rowb + rlo);
      short8 pf1 = *(const short8*)((const char*)pw + rowb + rhi);

#pragma unroll
      for (int fd = 0; fd < 4; ++fd) {
        cacc[fd] = mfma16(pf0, vf[2 * fd], cacc[fd]);
        cacc[fd] = mfma16(pf1, vf[2 * fd + 1], cacc[fd]);
      }
    }
    __syncthreads();
    cur ^= 1;
  }

  lsA += __shfl_xor(lsA, 16, 64); lsA += __shfl_xor(lsA, 32, 64);
  lsB += __shfl_xor(lsB, 16, 64); lsB += __shfl_xor(lsB, 32, 64);
  float linvA[4], linvB[4];
#pragma unroll
  for (int r = 0; r < 4; ++r) {
    linvA[r] = 1.0f / __shfl(lsA, lg * 4 + r, 64);
    linvB[r] = 1.0f / __shfl(lsB, lg * 4 + r, 64);
  }
  const int orow = b * Sn + qt * 128 + wave * 16 + lg * 4;
#pragma unroll
  for (int fd = 0; fd < 4; ++fd) {
    int col = h * 64 + fd * 16 + lr;
#pragma unroll
    for (int r = 0; r < 4; ++r) {
      ctx[(size_t)(orow + r) * Dn + col] = f2bf(caccA[fd][r] * linvA[r]);
      ctx[(size_t)(orow + 64 + r) * Dn + col] = f2bf(caccB[fd][r] * linvB[r]);
    }
  }
}

// ---------------- LayerNorm: one wave per row ----------------

__global__ __launch_bounds__(256)
void ln_kernel(const float* __restrict__ a, const float* __restrict__ bsrc,
               const float* __restrict__ alpha, const float* __restrict__ beta,
               float* __restrict__ outf, u16* __restrict__ outb) {
  const int wave = threadIdx.x >> 6, lane = threadIdx.x & 63;
  const size_t base = ((size_t)blockIdx.x * 4 + wave) * Dn;
  const int o = lane * 4;
  f32x4 v[3];
  float s = 0.f, q = 0.f;
#pragma unroll
  for (int j = 0; j < 3; ++j) {
    f32x4 av = *(const f32x4*)(a + base + j * 256 + o);
    f32x4 bv = *(const f32x4*)(bsrc + base + j * 256 + o);
    f32x4 x = av + bv;
    v[j] = x;
    s += (x[0] + x[1]) + (x[2] + x[3]);
    q += (x[0] * x[0] + x[1] * x[1]) + (x[2] * x[2] + x[3] * x[3]);
  }
#pragma unroll
  for (int sh = 1; sh < 64; sh <<= 1) {
    s += __shfl_xor(s, sh, 64);
    q += __shfl_xor(q, sh, 64);
  }
  const float mean = s * (1.f / 768.f);
  float var = (q - 768.f * mean * mean) * (1.f / 767.f);
  var = fmaxf(var, 0.f);
  const float rden = 1.f / (sqrtf(var) + EPS);
#pragma unroll
  for (int j = 0; j < 3; ++j) {
    f32x4 al = *(const f32x4*)(alpha + j * 256 + o);
    f32x4 be = *(const f32x4*)(beta + j * 256 + o);
    f32x4 y;
#pragma unroll
    for (int k = 0; k < 4; ++k)
      y[k] = al[k] * (v[j][k] - mean) * rden + be[k];
    *(f32x4*)(outf + base + j * 256 + o) = y;
    if (outb) {
      u32x2 w;
      w[0] = pk_bf16(y[0], y[1]);
      w[1] = pk_bf16(y[2], y[3]);
      *(u32x2*)(outb + base + j * 256 + o) = w;
    }
  }
}

// ---------------- launch ----------------

extern "C" void kernel_launch(void* const* d_in, const int* in_sizes, int n_in,
                              void* d_out, int out_size, void* d_ws, size_t ws_size,
                              hipStream_t stream) {
  (void)in_sizes; (void)n_in; (void)out_size; (void)ws_size;
  const float* x    = (const float*)d_in[0];
  const int*   mask = (const int*)d_in[1];
  const float* wq   = (const float*)d_in[2];
  const float* wk   = (const float*)d_in[3];
  const float* wv   = (const float*)d_in[4];
  const float* wo   = (const float*)d_in[5];
  const float* w1   = (const float*)d_in[6];
  const float* b1   = (const float*)d_in[7];
  const float* w2   = (const float*)d_in[8];
  const float* b2   = (const float*)d_in[9];
  const float* ln1a = (const float*)d_in[10];
  const float* ln1b = (const float*)d_in[11];
  const float* ln2a = (const float*)d_in[12];
  const float* ln2b = (const float*)d_in[13];
  float* out = (float*)d_out;

  char* ws = (char*)d_ws;
  size_t off = 0;
  auto alloc = [&](size_t bytes) -> void* {
    void* p = ws + off;
    off += (bytes + 255) & ~(size_t)255;
    return p;
  };
  u16* xb    = (u16*)alloc((size_t)BS * Dn * 2);      // reused as ctx later
  u16* wqkvT = (u16*)alloc((size_t)2304 * Dn * 2);
  u16* woT   = (u16*)alloc((size_t)Dn * Dn * 2);
  u16* w1T   = (u16*)alloc((size_t)DFFn * Dn * 2);
  u16* w2T   = (u16*)alloc((size_t)Dn * DFFn * 2);
  u16* qkv   = (u16*)alloc((size_t)BS * 2304 * 2);
  u16* vt    = (u16*)alloc((size_t)48 * 64 * Sn * 2);
  float* x1f = (float*)alloc((size_t)BS * Dn * 4);
  u16* x1b   = (u16*)alloc((size_t)BS * Dn * 2);
  u16* ff1   = (u16*)alloc((size_t)BS * DFFn * 2);
  u16* ctx   = xb;

  dim3 blk256(256), blk512(512);
  dim3 wblk(32, 8);
  cvt_x_kernel<<<dim3(BS * Dn / 8 / 256), blk256, 0, stream>>>(x, xb);
  wtrans_kernel<<<dim3(24, 24), wblk, 0, stream>>>(wq, wqkvT,               Dn, Dn, C1);
  wtrans_kernel<<<dim3(24, 24), wblk, 0, stream>>>(wk, wqkvT + 768 * 768,   Dn, Dn, 1.f);
  wtrans_kernel<<<dim3(24, 24), wblk, 0, stream>>>(wv, wqkvT + 2 * 768 * 768, Dn, Dn, 1.f);
  wtrans_kernel<<<dim3(24, 24), wblk, 0, stream>>>(wo, woT, Dn, Dn, 1.f);
  wtrans_kernel<<<dim3(96, 24), wblk, 0, stream>>>(w1, w1T, Dn, DFFn, 1.f);
  wtrans_kernel<<<dim3(24, 96), wblk, 0, stream>>>(w2, w2T, DFFn, Dn, 1.f);

  // qkv = xb @ [wq'|wk|wv]   (BM=256: grid 18x32 = 576)
  gemm_kernel<256, true, false, false><<<dim3(576), blk512, 0, stream>>>(xb, wqkvT, nullptr, qkv, 2304, 768, 18);
  vtrans_kernel<<<dim3(32, 48), blk256, 0, stream>>>(qkv, vt);
  attn_kernel<<<dim3(768), blk256, 0, stream>>>(qkv, vt, mask, ctx);
  // attn_out = ctx @ wo   (BM=128: grid 6x64 = 384)
  gemm_kernel<128, false, false, false><<<dim3(384), blk256, 0, stream>>>(ctx, woT, nullptr, out, 768, 768, 6);
  ln_kernel<<<dim3(BS / 4), blk256, 0, stream>>>(x, out, ln1a, ln1b, x1f, x1b);
  // ff1 = relu(x1 @ w1 + b1)   (BM=256: grid 24x32 = 768)
  gemm_kernel<256, true, true, true><<<dim3(768), blk512, 0, stream>>>(x1b, w1T, b1, ff1, 3072, 768, 24);
  // ff2 = ff1 @ w2 + b2   (BM=128: grid 6x64 = 384)
  gemm_kernel<128, false, false, true><<<dim3(384), blk256, 0, stream>>>(ff1, w2T, b2, out, 768, 3072, 6);
  ln_kernel<<<dim3(BS / 4), blk256, 0, stream>>>(x1f, out, ln2a, ln2b, out, nullptr);
}

// Round 6
// 281.279 us; speedup vs baseline: 1.1295x; 1.1295x over previous
//
#include <hip/hip_runtime.h>
#include <stdint.h>

#define DEV __device__ __forceinline__

typedef uint16_t u16;
typedef __attribute__((ext_vector_type(8))) short short8;
typedef __attribute__((ext_vector_type(4))) float f32x4;
typedef __attribute__((ext_vector_type(8))) __bf16 bf16x8;
typedef __attribute__((ext_vector_type(4))) int int4v;
typedef __attribute__((ext_vector_type(2))) unsigned int u32x2;

static constexpr int Bn = 4, Sn = 2048, Dn = 768, Hn = 12, DFFn = 3072;
static constexpr int BS = Bn * Sn;   // 8192 tokens
static constexpr float EPS = 1e-6f;
static constexpr float C1 = 0.18033688011112042f;   // 0.125 * log2(e)
static constexpr float SHIFT = 11.541560327111707f; // 8 * log2(e)

DEV u16 f2bf(float f) {
  union { float f; uint32_t u; } cv; cv.f = f;
  uint32_t u = cv.u;
  u += 0x7FFFu + ((u >> 16) & 1u);   // round-to-nearest-even
  return (u16)(u >> 16);
}

DEV uint32_t pk_bf16(float a, float b) {
  union { __bf16 h[2]; uint32_t u; } cv;
  cv.h[0] = (__bf16)a; cv.h[1] = (__bf16)b;
  return cv.u;
}

DEV float exp2_raw(float x) {
  float r;
  asm("v_exp_f32 %0, %1" : "=v"(r) : "v"(x));
  return r;
}

DEV f32x4 mfma16(short8 a, short8 b, f32x4 c) {
  return __builtin_amdgcn_mfma_f32_16x16x32_bf16(
      __builtin_bit_cast(bf16x8, a), __builtin_bit_cast(bf16x8, b), c, 0, 0, 0);
}

DEV void glds16(const void* g, void* l) {
  __builtin_amdgcn_global_load_lds(
      (const __attribute__((address_space(1))) void*)g,
      (__attribute__((address_space(3))) void*)l, 16, 0, 0);
}

DEV void barf() {
  asm volatile("" ::: "memory");
  __builtin_amdgcn_s_barrier();
  asm volatile("" ::: "memory");
}
#define WAITV(n) asm volatile("s_waitcnt vmcnt(" #n ")" ::: "memory")

// inverse of slot u = (r*4 + s) ^ (r&7); valid for r < 256
DEV void inv_swz(int u, int& r, int& s) {
  r = ((u >> 2) & 0x1FE) | (((u >> 2) ^ (u >> 4)) & 1);
  s = ((u ^ (u >> 2) ^ (u >> 4)) & 1) | ((u ^ (u >> 2)) & 2);
}

// ---------------- converts / transposes ----------------

__global__ void cvt_x_kernel(const float* __restrict__ in, u16* __restrict__ out) {
  size_t i = (size_t)blockIdx.x * 256 + threadIdx.x;
  const f32x4* p = (const f32x4*)in + i * 2;
  f32x4 a = p[0], b = p[1];
  short8 o;
  o[0] = (short)f2bf(a[0]); o[1] = (short)f2bf(a[1]);
  o[2] = (short)f2bf(a[2]); o[3] = (short)f2bf(a[3]);
  o[4] = (short)f2bf(b[0]); o[5] = (short)f2bf(b[1]);
  o[6] = (short)f2bf(b[2]); o[7] = (short)f2bf(b[3]);
  *(short8*)(out + i * 8) = o;
}

// four 768x768 weights [K][N] fp32 -> out[z][N][K] bf16 (z=0 scaled by C1)
__global__ void wtrans4_kernel(const float* __restrict__ w0, const float* __restrict__ w1,
                               const float* __restrict__ w2, const float* __restrict__ w3,
                               u16* __restrict__ out) {
  __shared__ float T[32][33];
  const int z = blockIdx.z;
  const float* w = (z == 0) ? w0 : (z == 1) ? w1 : (z == 2) ? w2 : w3;
  const float scale = (z == 0) ? C1 : 1.f;
  u16* o = out + (size_t)z * Dn * Dn;
  int tx = threadIdx.x, ty = threadIdx.y;
  int n0 = blockIdx.x * 32, k0 = blockIdx.y * 32;
#pragma unroll
  for (int i = 0; i < 4; ++i)
    T[ty + 8 * i][tx] = w[(size_t)(k0 + ty + 8 * i) * Dn + n0 + tx];
  __syncthreads();
#pragma unroll
  for (int i = 0; i < 4; ++i)
    o[(size_t)(n0 + ty + 8 * i) * Dn + k0 + tx] = f2bf(T[tx][ty + 8 * i] * scale);
}

// w[K][N] fp32 -> out[N][K] bf16
__global__ void wtrans_kernel(const float* __restrict__ w, u16* __restrict__ out,
                              int K, int N) {
  __shared__ float T[32][33];
  int tx = threadIdx.x, ty = threadIdx.y;
  int n0 = blockIdx.x * 32, k0 = blockIdx.y * 32;
#pragma unroll
  for (int i = 0; i < 4; ++i)
    T[ty + 8 * i][tx] = w[(size_t)(k0 + ty + 8 * i) * N + n0 + tx];
  __syncthreads();
#pragma unroll
  for (int i = 0; i < 4; ++i)
    out[(size_t)(n0 + ty + 8 * i) * K + k0 + tx] = f2bf(T[tx][ty + 8 * i]);
}

// qkv[token][2304], V section -> vt[bh][dk=64][S]
__global__ void vtrans_kernel(const u16* __restrict__ qkv, u16* __restrict__ vt) {
  __shared__ u16 T[64][72];
  const int tid = threadIdx.x;
  const int bh = blockIdx.y, b = bh / Hn, h = bh % Hn;
  const int s0 = blockIdx.x * 64;
  {
    int sl = tid >> 2, d0 = (tid & 3) * 16;
    const u16* src = qkv + (size_t)(b * Sn + s0 + sl) * 2304 + 1536 + h * 64 + d0;
    short8 v0 = *(const short8*)src;
    short8 v1 = *(const short8*)(src + 8);
    *(short8*)&T[sl][d0] = v0;
    *(short8*)&T[sl][d0 + 8] = v1;
  }
  __syncthreads();
  {
    int dk = tid >> 2, sl0 = (tid & 3) * 16;
    short8 o0, o1;
#pragma unroll
    for (int j = 0; j < 8; ++j) {
      o0[j] = (short)T[sl0 + j][dk];
      o1[j] = (short)T[sl0 + 8 + j][dk];
    }
    u16* dst = vt + (size_t)(bh * 64 + dk) * Sn + s0 + sl0;
    *(short8*)dst = o0;
    *(short8*)(dst + 8) = o1;
  }
}

// ==== GEMM BMx128, BK=32, depth-2 prefetch (3 LDS buffers), 1 barrier/tile ===
// C[M][N] = A[M][K] * Bt[N][K]^T.  XCD-aware block decode.

template<int BM, bool OUT_BF16, bool RELU, bool HAS_BIAS>
__global__ __launch_bounds__(BM * 2, 4)
void gemm_kernel(const u16* __restrict__ A, const u16* __restrict__ Bt,
                 const float* __restrict__ bias, void* __restrict__ Cout,
                 int N, int K, int gx) {
  constexpr int ABYTES = BM * 64;          // A bytes per buffer (BM x 32 bf16)
  constexpr int BUFSZ = ABYTES + 8192;     // + B (128 x 32 bf16)
  __shared__ char lds[3 * BUFSZ];
  const int tid = threadIdx.x;
  const int wave = tid >> 6, lane = tid & 63;
  const int lr = lane & 15, lg = lane >> 4;
  const int wr = wave >> 1, wc = wave & 1;

  const int kk = blockIdx.x >> 3, xcd = blockIdx.x & 7;
  const int row0 = (xcd + 8 * (kk / gx)) * BM, col0 = (kk % gx) * 128;

  size_t aofs[2], bofs[2];
#pragma unroll
  for (int i = 0; i < 2; ++i) {
    int r, s;
    inv_swz(tid + i * (BM * 2), r, s);
    aofs[i] = (size_t)(row0 + r) * K + s * 8;
  }
  {
    int r, s;
    inv_swz(tid, r, s);
    bofs[0] = (size_t)(col0 + r) * K + s * 8;
    if (BM == 128) {
      inv_swz(tid + 256, r, s);
      bofs[1] = (size_t)(col0 + r) * K + s * 8;
    }
  }
  const int aD0 = wave * 1024, aD1 = BM * 32 + wave * 1024;

  int aB[4], bB[4];
#pragma unroll
  for (int mi = 0; mi < 4; ++mi) {
    int row = wr * 64 + mi * 16 + lr;
    aB[mi] = ((row << 6) | (lg << 4)) ^ ((row & 7) << 4);
  }
#pragma unroll
  for (int nj = 0; nj < 4; ++nj) {
    int row = wc * 64 + nj * 16 + lr;
    bB[nj] = ((row << 6) | (lg << 4)) ^ ((row & 7) << 4);
  }

  f32x4 acc[4][4];
#pragma unroll
  for (int i = 0; i < 4; ++i)
#pragma unroll
    for (int j = 0; j < 4; ++j) acc[i][j] = (f32x4){0.f, 0.f, 0.f, 0.f};

  const int NT = K >> 5;
  auto stage = [&](char* buf, int kb) {
    glds16(A + aofs[0] + kb, buf + aD0);
    glds16(A + aofs[1] + kb, buf + aD1);
    glds16(Bt + bofs[0] + kb, buf + ABYTES + wave * 1024);
    if (BM == 128)
      glds16(Bt + bofs[1] + kb, buf + ABYTES + 4096 + wave * 1024);
  };

  char* b0 = lds;              // read target (tile t)
  char* b1 = lds + BUFSZ;      // tile t+1 in flight
  char* b2 = lds + 2 * BUFSZ;  // stage target (tile t+2)
  stage(b0, 0);
  stage(b1, 32);
  for (int t = 0; t < NT; ++t) {
    // wait for tile t's loads (oldest L), leave tile t+1's in flight
    if (t < NT - 1) {
      if (BM == 256) WAITV(3); else WAITV(4);
    } else {
      WAITV(0);
    }
    barf();
    if (t + 2 < NT) stage(b2, (t + 2) * 32);
    short8 a_[4], b_[4];
#pragma unroll
    for (int mi = 0; mi < 4; ++mi)
      a_[mi] = *(const short8*)(b0 + aB[mi]);
#pragma unroll
    for (int nj = 0; nj < 4; ++nj)
      b_[nj] = *(const short8*)(b0 + ABYTES + bB[nj]);
    __builtin_amdgcn_s_setprio(1);
#pragma unroll
    for (int mi = 0; mi < 4; ++mi)
#pragma unroll
      for (int nj = 0; nj < 4; ++nj)
        acc[mi][nj] = mfma16(a_[mi], b_[nj], acc[mi][nj]);
    __builtin_amdgcn_s_setprio(0);
    char* tmp = b0; b0 = b1; b1 = b2; b2 = tmp;
  }

#pragma unroll
  for (int mi = 0; mi < 4; ++mi) {
    int row = row0 + wr * 64 + mi * 16 + lg * 4;
#pragma unroll
    for (int nj = 0; nj < 4; ++nj) {
      int col = col0 + wc * 64 + nj * 16 + lr;
      float bv = HAS_BIAS ? bias[col] : 0.f;
#pragma unroll
      for (int r = 0; r < 4; ++r) {
        float v = acc[mi][nj][r] + bv;
        if (RELU) v = fmaxf(v, 0.f);
        size_t o = (size_t)(row + r) * N + col;
        if (OUT_BF16) ((u16*)Cout)[o] = f2bf(v);
        else ((float*)Cout)[o] = v;
      }
    }
  }
}

// ---------------- flash attention (R4 version, restored) ----------------
// 128 q-rows/block, static-shift softmax with scale folded into wq
// (Q' = Q * 0.125*log2e) and shift folded into the QK accumulator init.

__global__ __launch_bounds__(256, 3)
void attn_kernel(const u16* __restrict__ qkv, const u16* __restrict__ vt,
                 const int* __restrict__ mask, u16* __restrict__ ctx) {
  __shared__ u16 kbuf[2][4096];
  __shared__ u16 vbuf[2][4096];
  __shared__ u16 pbuf[4][2][1024];

  const int tid = threadIdx.x;
  const int wave = tid >> 6, lane = tid & 63;
  const int lr = lane & 15, lg = lane >> 4;

  const int lin = blockIdx.x;
  const int logical = (lin & 7) * 96 + (lin >> 3);
  const int qt = logical & 15;
  const int bh = logical >> 4;
  const int b = bh / Hn, h = bh % Hn;

  int ok;
  {
    const int4v* ms = (const int4v*)(mask + b * Sn);
    int4v m0 = ms[tid * 2], m1 = ms[tid * 2 + 1];
    ok = m0[0] && m0[1] && m0[2] && m0[3] && m1[0] && m1[1] && m1[2] && m1[3];
  }
  const bool allones = (__syncthreads_and(ok) != 0);

  const int cu = (lane & 7) ^ (lane >> 3);
  const int r0 = wave * 16 + (lane >> 3);
  const u16* kg0 = qkv + (size_t)(b * Sn + r0) * 2304 + 768 + h * 64 + cu * 8;
  const u16* vg0 = vt + (size_t)(bh * 64 + r0) * Sn + cu * 8;
  u16* kd = &kbuf[0][0] + wave * 1024;
  u16* vd = &vbuf[0][0] + wave * 1024;

  const size_t qrowA = (size_t)(b * Sn + qt * 128 + wave * 16 + lr) * 2304 + h * 64 + lg * 8;
  short8 qa0 = *(const short8*)(qkv + qrowA);
  short8 qa1 = *(const short8*)(qkv + qrowA + 32);
  const size_t qrowB = qrowA + (size_t)64 * 2304;
  short8 qb0 = *(const short8*)(qkv + qrowB);
  short8 qb1 = *(const short8*)(qkv + qrowB + 32);

  const int rlo = (lg ^ (lr & 7)) << 4;
  const int rhi = ((4 + lg) ^ (lr & 7)) << 4;
  const int rowb = lr * 128;

  f32x4 caccA[4], caccB[4];
#pragma unroll
  for (int i = 0; i < 4; ++i) {
    caccA[i] = (f32x4){0.f, 0.f, 0.f, 0.f};
    caccB[i] = (f32x4){0.f, 0.f, 0.f, 0.f};
  }
  float lsA = 0.f, lsB = 0.f;

  u16* pwA = &pbuf[wave][0][0];
  u16* pwB = &pbuf[wave][1][0];
  const int pwr = (lg >> 1), pwo = 8 * (lg & 1);

  auto stage = [&](int bf, int c) {
    const u16* kg = kg0 + (size_t)c * 64 * 2304;
    const u16* vg = vg0 + c * 64;
    glds16(kg,            kd + bf * 4096);
    glds16(kg + 8 * 2304, kd + bf * 4096 + 512);
    glds16(vg,            vd + bf * 4096);
    glds16(vg + 8 * Sn,   vd + bf * 4096 + 512);
  };

  stage(0, 0);
  __syncthreads();
  int cur = 0;
  for (int c = 0; c < 32; ++c) {
    if (c + 1 < 32) stage(cur ^ 1, c + 1);
    const char* kb = (const char*)&kbuf[cur][0];
    const char* vb = (const char*)&vbuf[cur][0];

    int4v mk[4];
    if (!allones) {
      const int4v* mp = (const int4v*)(mask + b * Sn + c * 64 + lg * 4);
#pragma unroll
      for (int f = 0; f < 4; ++f) mk[f] = mp[f * 4];
    }

#pragma unroll
    for (int set = 0; set < 2; ++set) {
      short8 q0 = set ? qb0 : qa0;
      short8 q1 = set ? qb1 : qa1;
      u16* pw = set ? pwB : pwA;
      f32x4* cacc = set ? caccB : caccA;
      float ls = 0.f;

      f32x4 sc[4];
#pragma unroll
      for (int f = 0; f < 4; ++f) {
        short8 k0 = *(const short8*)(kb + f * 2048 + rowb + rlo);
        short8 k1 = *(const short8*)(kb + f * 2048 + rowb + rhi);
        f32x4 z = (f32x4){-SHIFT, -SHIFT, -SHIFT, -SHIFT};
        z = mfma16(k0, q0, z);
        z = mfma16(k1, q1, z);
        sc[f] = z;
      }
      if (!allones) {
#pragma unroll
        for (int f = 0; f < 4; ++f)
#pragma unroll
          for (int r = 0; r < 4; ++r)
            sc[f][r] = mk[f][r] ? sc[f][r] : -1.0e5f;
      }
#pragma unroll
      for (int f = 0; f < 4; ++f) {
#pragma unroll
        for (int r = 0; r < 4; ++r) {
          float p = exp2_raw(sc[f][r]);
          sc[f][r] = p;
          ls += p;
        }
      }
      if (set) lsB += ls; else lsA += ls;

#pragma unroll
      for (int f = 0; f < 4; ++f) {
        u32x2 w;
        w[0] = pk_bf16(sc[f][0], sc[f][1]);
        w[1] = pk_bf16(sc[f][2], sc[f][3]);
        *(u32x2*)((char*)pw + rowb + (((2 * f + pwr) ^ (lr & 7)) << 4) + pwo) = w;
      }
      short8 pf0 = *(const short8*)((const char*)pw + rowb + rlo);
      short8 pf1 = *(const short8*)((const char*)pw + rowb + rhi);

#pragma unroll
      for (int fd = 0; fd < 4; ++fd) {
        short8 v0 = *(const short8*)(vb + fd * 2048 + rowb + rlo);
        short8 v1 = *(const short8*)(vb + fd * 2048 + rowb + rhi);
        cacc[fd] = mfma16(pf0, v0, cacc[fd]);
        cacc[fd] = mfma16(pf1, v1, cacc[fd]);
      }
    }
    __syncthreads();
    cur ^= 1;
  }

  lsA += __shfl_xor(lsA, 16, 64); lsA += __shfl_xor(lsA, 32, 64);
  lsB += __shfl_xor(lsB, 16, 64); lsB += __shfl_xor(lsB, 32, 64);
  float linvA[4], linvB[4];
#pragma unroll
  for (int r = 0; r < 4; ++r) {
    linvA[r] = 1.0f / __shfl(lsA, lg * 4 + r, 64);
    linvB[r] = 1.0f / __shfl(lsB, lg * 4 + r, 64);
  }
  const int orow = b * Sn + qt * 128 + wave * 16 + lg * 4;
#pragma unroll
  for (int fd = 0; fd < 4; ++fd) {
    int col = h * 64 + fd * 16 + lr;
#pragma unroll
    for (int r = 0; r < 4; ++r) {
      ctx[(size_t)(orow + r) * Dn + col] = f2bf(caccA[fd][r] * linvA[r]);
      ctx[(size_t)(orow + 64 + r) * Dn + col] = f2bf(caccB[fd][r] * linvB[r]);
    }
  }
}

// ---------------- LayerNorm: one wave per row ----------------

__global__ __launch_bounds__(256)
void ln_kernel(const float* __restrict__ a, const float* __restrict__ bsrc,
               const float* __restrict__ alpha, const float* __restrict__ beta,
               float* __restrict__ outf, u16* __restrict__ outb) {
  const int wave = threadIdx.x >> 6, lane = threadIdx.x & 63;
  const size_t base = ((size_t)blockIdx.x * 4 + wave) * Dn;
  const int o = lane * 4;
  f32x4 v[3];
  float s = 0.f, q = 0.f;
#pragma unroll
  for (int j = 0; j < 3; ++j) {
    f32x4 av = *(const f32x4*)(a + base + j * 256 + o);
    f32x4 bv = *(const f32x4*)(bsrc + base + j * 256 + o);
    f32x4 x = av + bv;
    v[j] = x;
    s += (x[0] + x[1]) + (x[2] + x[3]);
    q += (x[0] * x[0] + x[1] * x[1]) + (x[2] * x[2] + x[3] * x[3]);
  }
#pragma unroll
  for (int sh = 1; sh < 64; sh <<= 1) {
    s += __shfl_xor(s, sh, 64);
    q += __shfl_xor(q, sh, 64);
  }
  const float mean = s * (1.f / 768.f);
  float var = (q - 768.f * mean * mean) * (1.f / 767.f);
  var = fmaxf(var, 0.f);
  const float rden = 1.f / (sqrtf(var) + EPS);
#pragma unroll
  for (int j = 0; j < 3; ++j) {
    f32x4 al = *(const f32x4*)(alpha + j * 256 + o);
    f32x4 be = *(const f32x4*)(beta + j * 256 + o);
    f32x4 y;
#pragma unroll
    for (int k = 0; k < 4; ++k)
      y[k] = al[k] * (v[j][k] - mean) * rden + be[k];
    *(f32x4*)(outf + base + j * 256 + o) = y;
    if (outb) {
      u32x2 w;
      w[0] = pk_bf16(y[0], y[1]);
      w[1] = pk_bf16(y[2], y[3]);
      *(u32x2*)(outb + base + j * 256 + o) = w;
    }
  }
}

// ---------------- launch ----------------

extern "C" void kernel_launch(void* const* d_in, const int* in_sizes, int n_in,
                              void* d_out, int out_size, void* d_ws, size_t ws_size,
                              hipStream_t stream) {
  (void)in_sizes; (void)n_in; (void)out_size; (void)ws_size;
  const float* x    = (const float*)d_in[0];
  const int*   mask = (const int*)d_in[1];
  const float* wq   = (const float*)d_in[2];
  const float* wk   = (const float*)d_in[3];
  const float* wv   = (const float*)d_in[4];
  const float* wo   = (const float*)d_in[5];
  const float* w1   = (const float*)d_in[6];
  const float* b1   = (const float*)d_in[7];
  const float* w2   = (const float*)d_in[8];
  const float* b2   = (const float*)d_in[9];
  const float* ln1a = (const float*)d_in[10];
  const float* ln1b = (const float*)d_in[11];
  const float* ln2a = (const float*)d_in[12];
  const float* ln2b = (const float*)d_in[13];
  float* out = (float*)d_out;

  char* ws = (char*)d_ws;
  size_t off = 0;
  auto alloc = [&](size_t bytes) -> void* {
    void* p = ws + off;
    off += (bytes + 255) & ~(size_t)255;
    return p;
  };
  u16* xb    = (u16*)alloc((size_t)BS * Dn * 2);      // reused as ctx later
  u16* wqkvT = (u16*)alloc((size_t)2304 * Dn * 2);
  u16* woT   = (u16*)alloc((size_t)Dn * Dn * 2);      // contiguous after wqkvT
  u16* w1T   = (u16*)alloc((size_t)DFFn * Dn * 2);
  u16* w2T   = (u16*)alloc((size_t)Dn * DFFn * 2);
  u16* qkv   = (u16*)alloc((size_t)BS * 2304 * 2);
  u16* vt    = (u16*)alloc((size_t)48 * 64 * Sn * 2);
  float* x1f = (float*)alloc((size_t)BS * Dn * 4);
  u16* x1b   = (u16*)alloc((size_t)BS * Dn * 2);
  u16* ff1   = (u16*)alloc((size_t)BS * DFFn * 2);
  u16* ctx   = xb;

  dim3 blk256(256), blk512(512);
  dim3 wblk(32, 8);
  cvt_x_kernel<<<dim3(BS * Dn / 8 / 256), blk256, 0, stream>>>(x, xb);
  // wq(scaled)/wk/wv/wo in one launch; wqkvT and woT are contiguous
  wtrans4_kernel<<<dim3(24, 24, 4), wblk, 0, stream>>>(wq, wk, wv, wo, wqkvT);
  wtrans_kernel<<<dim3(96, 24), wblk, 0, stream>>>(w1, w1T, Dn, DFFn);
  wtrans_kernel<<<dim3(24, 96), wblk, 0, stream>>>(w2, w2T, DFFn, Dn);

  // qkv = xb @ [wq'|wk|wv]   (BM=256: grid 18x32 = 576)
  gemm_kernel<256, true, false, false><<<dim3(576), blk512, 0, stream>>>(xb, wqkvT, nullptr, qkv, 2304, 768, 18);
  vtrans_kernel<<<dim3(32, 48), blk256, 0, stream>>>(qkv, vt);
  attn_kernel<<<dim3(768), blk256, 0, stream>>>(qkv, vt, mask, ctx);
  // attn_out = ctx @ wo   (BM=128: grid 6x64 = 384)
  gemm_kernel<128, false, false, false><<<dim3(384), blk256, 0, stream>>>(ctx, woT, nullptr, out, 768, 768, 6);
  ln_kernel<<<dim3(BS / 4), blk256, 0, stream>>>(x, out, ln1a, ln1b, x1f, x1b);
  // ff1 = relu(x1 @ w1 + b1)   (BM=256: grid 24x32 = 768)
  gemm_kernel<256, true, true, true><<<dim3(768), blk512, 0, stream>>>(x1b, w1T, b1, ff1, 3072, 768, 24);
  // ff2 = ff1 @ w2 + b2   (BM=128: grid 6x64 = 384)
  gemm_kernel<128, false, false, true><<<dim3(384), blk256, 0, stream>>>(ff1, w2T, b2, out, 768, 3072, 6);
  ln_kernel<<<dim3(BS / 4), blk256, 0, stream>>>(x1f, out, ln2a, ln2b, out, nullptr);
}

// Round 8
// 273.484 us; speedup vs baseline: 1.1617x; 1.0285x over previous
//
#include <hip/hip_runtime.h>
#include <stdint.h>

#define DEV __device__ __forceinline__

typedef uint16_t u16;
typedef __attribute__((ext_vector_type(8))) short short8;
typedef __attribute__((ext_vector_type(4))) float f32x4;
typedef __attribute__((ext_vector_type(8))) __bf16 bf16x8;
typedef __attribute__((ext_vector_type(4))) int int4v;
typedef __attribute__((ext_vector_type(2))) unsigned int u32x2;
typedef __attribute__((ext_vector_type(4))) short s16x4;

static constexpr int Bn = 4, Sn = 2048, Dn = 768, Hn = 12, DFFn = 3072;
static constexpr int BS = Bn * Sn;   // 8192 tokens
static constexpr float EPS = 1e-6f;
static constexpr float C1 = 0.18033688011112042f;   // 0.125 * log2(e)
static constexpr float SHIFT = 11.541560327111707f; // 8 * log2(e)

DEV u16 f2bf(float f) {
  union { float f; uint32_t u; } cv; cv.f = f;
  uint32_t u = cv.u;
  u += 0x7FFFu + ((u >> 16) & 1u);   // round-to-nearest-even
  return (u16)(u >> 16);
}

DEV uint32_t pk_bf16(float a, float b) {
  union { __bf16 h[2]; uint32_t u; } cv;
  cv.h[0] = (__bf16)a; cv.h[1] = (__bf16)b;
  return cv.u;
}

DEV float exp2_raw(float x) {
  float r;
  asm("v_exp_f32 %0, %1" : "=v"(r) : "v"(x));
  return r;
}

DEV float bf2f(u16 v) {
  union { uint32_t u; float f; } cv; cv.u = (uint32_t)v << 16;
  return cv.f;
}

DEV f32x4 mfma16(short8 a, short8 b, f32x4 c) {
  return __builtin_amdgcn_mfma_f32_16x16x32_bf16(
      __builtin_bit_cast(bf16x8, a), __builtin_bit_cast(bf16x8, b), c, 0, 0, 0);
}

DEV void glds16(const void* g, void* l) {
  __builtin_amdgcn_global_load_lds(
      (const __attribute__((address_space(1))) void*)g,
      (__attribute__((address_space(3))) void*)l, 16, 0, 0);
}

DEV void barf() {
  asm volatile("" ::: "memory");
  __builtin_amdgcn_s_barrier();
  asm volatile("" ::: "memory");
}
#define WAITV(n) asm volatile("s_waitcnt vmcnt(" #n ")" ::: "memory")

// inverse of slot u = (r*4 + s) ^ (r&7); valid for r < 256
DEV void inv_swz(int u, int& r, int& s) {
  r = ((u >> 2) & 0x1FE) | (((u >> 2) ^ (u >> 4)) & 1);
  s = ((u ^ (u >> 2) ^ (u >> 4)) & 1) | ((u ^ (u >> 2)) & 2);
}

// ---------------- converts / transposes ----------------

__global__ void cvt_x_kernel(const float* __restrict__ in, u16* __restrict__ out) {
  size_t i = (size_t)blockIdx.x * 256 + threadIdx.x;
  const f32x4* p = (const f32x4*)in + i * 2;
  f32x4 a = p[0], b = p[1];
  short8 o;
  o[0] = (short)f2bf(a[0]); o[1] = (short)f2bf(a[1]);
  o[2] = (short)f2bf(a[2]); o[3] = (short)f2bf(a[3]);
  o[4] = (short)f2bf(b[0]); o[5] = (short)f2bf(b[1]);
  o[6] = (short)f2bf(b[2]); o[7] = (short)f2bf(b[3]);
  *(short8*)(out + i * 8) = o;
}

// four 768x768 weights [K][N] fp32 -> out[z][N][K] bf16 (z=0 scaled by C1)
__global__ void wtrans4_kernel(const float* __restrict__ w0, const float* __restrict__ w1,
                               const float* __restrict__ w2, const float* __restrict__ w3,
                               u16* __restrict__ out) {
  __shared__ float T[32][33];
  const int z = blockIdx.z;
  const float* w = (z == 0) ? w0 : (z == 1) ? w1 : (z == 2) ? w2 : w3;
  const float scale = (z == 0) ? C1 : 1.f;
  u16* o = out + (size_t)z * Dn * Dn;
  int tx = threadIdx.x, ty = threadIdx.y;
  int n0 = blockIdx.x * 32, k0 = blockIdx.y * 32;
#pragma unroll
  for (int i = 0; i < 4; ++i)
    T[ty + 8 * i][tx] = w[(size_t)(k0 + ty + 8 * i) * Dn + n0 + tx];
  __syncthreads();
#pragma unroll
  for (int i = 0; i < 4; ++i)
    o[(size_t)(n0 + ty + 8 * i) * Dn + k0 + tx] = f2bf(T[tx][ty + 8 * i] * scale);
}

// w[K][N] fp32 -> out[N][K] bf16
__global__ void wtrans_kernel(const float* __restrict__ w, u16* __restrict__ out,
                              int K, int N) {
  __shared__ float T[32][33];
  int tx = threadIdx.x, ty = threadIdx.y;
  int n0 = blockIdx.x * 32, k0 = blockIdx.y * 32;
#pragma unroll
  for (int i = 0; i < 4; ++i)
    T[ty + 8 * i][tx] = w[(size_t)(k0 + ty + 8 * i) * N + n0 + tx];
  __syncthreads();
#pragma unroll
  for (int i = 0; i < 4; ++i)
    out[(size_t)(n0 + ty + 8 * i) * K + k0 + tx] = f2bf(T[tx][ty + 8 * i]);
}

// ==== GEMM BMx128, BK=32, depth-2 prefetch (3 LDS buffers), 1 barrier/tile ===
// C[M][N] = A[M][K] * Bt[N][K]^T.  XCD-aware block decode.
// VFUSE: tiles with col0 >= 1536 (the V section of the qkv projection) are
// written directly to vt[bh][dk=64][S] (fused V-transpose) instead of C.

template<int BM, bool OUT_BF16, bool RELU, bool HAS_BIAS, bool VFUSE>
__global__ __launch_bounds__(BM * 2, 4)
void gemm_kernel(const u16* __restrict__ A, const u16* __restrict__ Bt,
                 const float* __restrict__ bias, void* __restrict__ Cout,
                 int N, int K, int gx, u16* __restrict__ vt) {
  constexpr int ABYTES = BM * 64;          // A bytes per buffer (BM x 32 bf16)
  constexpr int BUFSZ = ABYTES + 8192;     // + B (128 x 32 bf16)
  __shared__ char lds[3 * BUFSZ];
  const int tid = threadIdx.x;
  const int wave = tid >> 6, lane = tid & 63;
  const int lr = lane & 15, lg = lane >> 4;
  const int wr = wave >> 1, wc = wave & 1;

  const int kk = blockIdx.x >> 3, xcd = blockIdx.x & 7;
  const int row0 = (xcd + 8 * (kk / gx)) * BM, col0 = (kk % gx) * 128;

  size_t aofs[2], bofs[2];
#pragma unroll
  for (int i = 0; i < 2; ++i) {
    int r, s;
    inv_swz(tid + i * (BM * 2), r, s);
    aofs[i] = (size_t)(row0 + r) * K + s * 8;
  }
  {
    int r, s;
    inv_swz(tid, r, s);
    bofs[0] = (size_t)(col0 + r) * K + s * 8;
    if (BM == 128) {
      inv_swz(tid + 256, r, s);
      bofs[1] = (size_t)(col0 + r) * K + s * 8;
    }
  }
  const int aD0 = wave * 1024, aD1 = BM * 32 + wave * 1024;

  int aB[4], bB[4];
#pragma unroll
  for (int mi = 0; mi < 4; ++mi) {
    int row = wr * 64 + mi * 16 + lr;
    aB[mi] = ((row << 6) | (lg << 4)) ^ ((row & 7) << 4);
  }
#pragma unroll
  for (int nj = 0; nj < 4; ++nj) {
    int row = wc * 64 + nj * 16 + lr;
    bB[nj] = ((row << 6) | (lg << 4)) ^ ((row & 7) << 4);
  }

  f32x4 acc[4][4];
#pragma unroll
  for (int i = 0; i < 4; ++i)
#pragma unroll
    for (int j = 0; j < 4; ++j) acc[i][j] = (f32x4){0.f, 0.f, 0.f, 0.f};

  const int NT = K >> 5;
  auto stage = [&](char* buf, int kb) {
    glds16(A + aofs[0] + kb, buf + aD0);
    glds16(A + aofs[1] + kb, buf + aD1);
    glds16(Bt + bofs[0] + kb, buf + ABYTES + wave * 1024);
    if (BM == 128)
      glds16(Bt + bofs[1] + kb, buf + ABYTES + 4096 + wave * 1024);
  };

  char* b0 = lds;              // read target (tile t)
  char* b1 = lds + BUFSZ;      // tile t+1 in flight
  char* b2 = lds + 2 * BUFSZ;  // stage target (tile t+2)
  stage(b0, 0);
  stage(b1, 32);
  for (int t = 0; t < NT; ++t) {
    if (t < NT - 1) {
      if (BM == 256) WAITV(3); else WAITV(4);
    } else {
      WAITV(0);
    }
    barf();
    if (t + 2 < NT) stage(b2, (t + 2) * 32);
    short8 a_[4], b_[4];
#pragma unroll
    for (int mi = 0; mi < 4; ++mi)
      a_[mi] = *(const short8*)(b0 + aB[mi]);
#pragma unroll
    for (int nj = 0; nj < 4; ++nj)
      b_[nj] = *(const short8*)(b0 + ABYTES + bB[nj]);
    __builtin_amdgcn_s_setprio(1);
#pragma unroll
    for (int mi = 0; mi < 4; ++mi)
#pragma unroll
      for (int nj = 0; nj < 4; ++nj)
        acc[mi][nj] = mfma16(a_[mi], b_[nj], acc[mi][nj]);
    __builtin_amdgcn_s_setprio(0);
    char* tmp = b0; b0 = b1; b1 = b2; b2 = tmp;
  }

  if (VFUSE && col0 >= 1536) {
    // V tile: write to vt[bh = b*12 + (col-1536)/64][dk = col%64][s = row%2048]
#pragma unroll
    for (int mi = 0; mi < 4; ++mi) {
      int row = row0 + wr * 64 + mi * 16 + lg * 4;
      int b = row >> 11, s = row & 2047;
#pragma unroll
      for (int nj = 0; nj < 4; ++nj) {
        int col = col0 + wc * 64 + nj * 16 + lr;
        int bh = b * Hn + ((col - 1536) >> 6), dk = col & 63;
        s16x4 v;
#pragma unroll
        for (int r = 0; r < 4; ++r) v[r] = (short)f2bf(acc[mi][nj][r]);
        *(s16x4*)(vt + (size_t)(bh * 64 + dk) * Sn + s) = v;
      }
    }
    return;
  }

#pragma unroll
  for (int mi = 0; mi < 4; ++mi) {
    int row = row0 + wr * 64 + mi * 16 + lg * 4;
#pragma unroll
    for (int nj = 0; nj < 4; ++nj) {
      int col = col0 + wc * 64 + nj * 16 + lr;
      float bv = HAS_BIAS ? bias[col] : 0.f;
#pragma unroll
      for (int r = 0; r < 4; ++r) {
        float v = acc[mi][nj][r] + bv;
        if (RELU) v = fmaxf(v, 0.f);
        size_t o = (size_t)(row + r) * N + col;
        if (OUT_BF16) ((u16*)Cout)[o] = f2bf(v);
        else ((float*)Cout)[o] = v;
      }
    }
  }
}

// ---------------- flash attention (R4/R6 version, frozen) ----------------

__global__ __launch_bounds__(256, 3)
void attn_kernel(const u16* __restrict__ qkv, const u16* __restrict__ vt,
                 const int* __restrict__ mask, u16* __restrict__ ctx) {
  __shared__ u16 kbuf[2][4096];
  __shared__ u16 vbuf[2][4096];
  __shared__ u16 pbuf[4][2][1024];

  const int tid = threadIdx.x;
  const int wave = tid >> 6, lane = tid & 63;
  const int lr = lane & 15, lg = lane >> 4;

  const int lin = blockIdx.x;
  const int logical = (lin & 7) * 96 + (lin >> 3);
  const int qt = logical & 15;
  const int bh = logical >> 4;
  const int b = bh / Hn, h = bh % Hn;

  int ok;
  {
    const int4v* ms = (const int4v*)(mask + b * Sn);
    int4v m0 = ms[tid * 2], m1 = ms[tid * 2 + 1];
    ok = m0[0] && m0[1] && m0[2] && m0[3] && m1[0] && m1[1] && m1[2] && m1[3];
  }
  const bool allones = (__syncthreads_and(ok) != 0);

  const int cu = (lane & 7) ^ (lane >> 3);
  const int r0 = wave * 16 + (lane >> 3);
  const u16* kg0 = qkv + (size_t)(b * Sn + r0) * 2304 + 768 + h * 64 + cu * 8;
  const u16* vg0 = vt + (size_t)(bh * 64 + r0) * Sn + cu * 8;
  u16* kd = &kbuf[0][0] + wave * 1024;
  u16* vd = &vbuf[0][0] + wave * 1024;

  const size_t qrowA = (size_t)(b * Sn + qt * 128 + wave * 16 + lr) * 2304 + h * 64 + lg * 8;
  short8 qa0 = *(const short8*)(qkv + qrowA);
  short8 qa1 = *(const short8*)(qkv + qrowA + 32);
  const size_t qrowB = qrowA + (size_t)64 * 2304;
  short8 qb0 = *(const short8*)(qkv + qrowB);
  short8 qb1 = *(const short8*)(qkv + qrowB + 32);

  const int rlo = (lg ^ (lr & 7)) << 4;
  const int rhi = ((4 + lg) ^ (lr & 7)) << 4;
  const int rowb = lr * 128;

  f32x4 caccA[4], caccB[4];
#pragma unroll
  for (int i = 0; i < 4; ++i) {
    caccA[i] = (f32x4){0.f, 0.f, 0.f, 0.f};
    caccB[i] = (f32x4){0.f, 0.f, 0.f, 0.f};
  }
  float lsA = 0.f, lsB = 0.f;

  u16* pwA = &pbuf[wave][0][0];
  u16* pwB = &pbuf[wave][1][0];
  const int pwr = (lg >> 1), pwo = 8 * (lg & 1);

  auto stage = [&](int bf, int c) {
    const u16* kg = kg0 + (size_t)c * 64 * 2304;
    const u16* vg = vg0 + c * 64;
    glds16(kg,            kd + bf * 4096);
    glds16(kg + 8 * 2304, kd + bf * 4096 + 512);
    glds16(vg,            vd + bf * 4096);
    glds16(vg + 8 * Sn,   vd + bf * 4096 + 512);
  };

  stage(0, 0);
  __syncthreads();
  int cur = 0;
  for (int c = 0; c < 32; ++c) {
    if (c + 1 < 32) stage(cur ^ 1, c + 1);
    const char* kb = (const char*)&kbuf[cur][0];
    const char* vb = (const char*)&vbuf[cur][0];

    int4v mk[4];
    if (!allones) {
      const int4v* mp = (const int4v*)(mask + b * Sn + c * 64 + lg * 4);
#pragma unroll
      for (int f = 0; f < 4; ++f) mk[f] = mp[f * 4];
    }

#pragma unroll
    for (int set = 0; set < 2; ++set) {
      short8 q0 = set ? qb0 : qa0;
      short8 q1 = set ? qb1 : qa1;
      u16* pw = set ? pwB : pwA;
      f32x4* cacc = set ? caccB : caccA;
      float ls = 0.f;

      f32x4 sc[4];
#pragma unroll
      for (int f = 0; f < 4; ++f) {
        short8 k0 = *(const short8*)(kb + f * 2048 + rowb + rlo);
        short8 k1 = *(const short8*)(kb + f * 2048 + rowb + rhi);
        f32x4 z = (f32x4){-SHIFT, -SHIFT, -SHIFT, -SHIFT};
        z = mfma16(k0, q0, z);
        z = mfma16(k1, q1, z);
        sc[f] = z;
      }
      if (!allones) {
#pragma unroll
        for (int f = 0; f < 4; ++f)
#pragma unroll
          for (int r = 0; r < 4; ++r)
            sc[f][r] = mk[f][r] ? sc[f][r] : -1.0e5f;
      }
#pragma unroll
      for (int f = 0; f < 4; ++f) {
#pragma unroll
        for (int r = 0; r < 4; ++r) {
          float p = exp2_raw(sc[f][r]);
          sc[f][r] = p;
          ls += p;
        }
      }
      if (set) lsB += ls; else lsA += ls;

#pragma unroll
      for (int f = 0; f < 4; ++f) {
        u32x2 w;
        w[0] = pk_bf16(sc[f][0], sc[f][1]);
        w[1] = pk_bf16(sc[f][2], sc[f][3]);
        *(u32x2*)((char*)pw + rowb + (((2 * f + pwr) ^ (lr & 7)) << 4) + pwo) = w;
      }
      short8 pf0 = *(const short8*)((const char*)pw + rowb + rlo);
      short8 pf1 = *(const short8*)((const char*)pw + rowb + rhi);

#pragma unroll
      for (int fd = 0; fd < 4; ++fd) {
        short8 v0 = *(const short8*)(vb + fd * 2048 + rowb + rlo);
        short8 v1 = *(const short8*)(vb + fd * 2048 + rowb + rhi);
        cacc[fd] = mfma16(pf0, v0, cacc[fd]);
        cacc[fd] = mfma16(pf1, v1, cacc[fd]);
      }
    }
    __syncthreads();
    cur ^= 1;
  }

  lsA += __shfl_xor(lsA, 16, 64); lsA += __shfl_xor(lsA, 32, 64);
  lsB += __shfl_xor(lsB, 16, 64); lsB += __shfl_xor(lsB, 32, 64);
  float linvA[4], linvB[4];
#pragma unroll
  for (int r = 0; r < 4; ++r) {
    linvA[r] = 1.0f / __shfl(lsA, lg * 4 + r, 64);
    linvB[r] = 1.0f / __shfl(lsB, lg * 4 + r, 64);
  }
  const int orow = b * Sn + qt * 128 + wave * 16 + lg * 4;
#pragma unroll
  for (int fd = 0; fd < 4; ++fd) {
    int col = h * 64 + fd * 16 + lr;
#pragma unroll
    for (int r = 0; r < 4; ++r) {
      ctx[(size_t)(orow + r) * Dn + col] = f2bf(caccA[fd][r] * linvA[r]);
      ctx[(size_t)(orow + 64 + r) * Dn + col] = f2bf(caccB[fd][r] * linvB[r]);
    }
  }
}

// -------- LayerNorm: one wave per row; residual source fp32 or bf16 --------

template<bool BSRC_BF16>
__global__ __launch_bounds__(256)
void ln_kernel(const float* __restrict__ a, const void* __restrict__ bsrc,
               const float* __restrict__ alpha, const float* __restrict__ beta,
               float* __restrict__ outf, u16* __restrict__ outb) {
  const int wave = threadIdx.x >> 6, lane = threadIdx.x & 63;
  const size_t base = ((size_t)blockIdx.x * 4 + wave) * Dn;
  const int o = lane * 4;
  f32x4 v[3];
  float s = 0.f, q = 0.f;
#pragma unroll
  for (int j = 0; j < 3; ++j) {
    f32x4 av = *(const f32x4*)(a + base + j * 256 + o);
    f32x4 bv;
    if (BSRC_BF16) {
      s16x4 bb = *(const s16x4*)((const u16*)bsrc + base + j * 256 + o);
#pragma unroll
      for (int k = 0; k < 4; ++k) bv[k] = bf2f((u16)bb[k]);
    } else {
      bv = *(const f32x4*)((const float*)bsrc + base + j * 256 + o);
    }
    f32x4 x = av + bv;
    v[j] = x;
    s += (x[0] + x[1]) + (x[2] + x[3]);
    q += (x[0] * x[0] + x[1] * x[1]) + (x[2] * x[2] + x[3] * x[3]);
  }
#pragma unroll
  for (int sh = 1; sh < 64; sh <<= 1) {
    s += __shfl_xor(s, sh, 64);
    q += __shfl_xor(q, sh, 64);
  }
  const float mean = s * (1.f / 768.f);
  float var = (q - 768.f * mean * mean) * (1.f / 767.f);
  var = fmaxf(var, 0.f);
  const float rden = 1.f / (sqrtf(var) + EPS);
#pragma unroll
  for (int j = 0; j < 3; ++j) {
    f32x4 al = *(const f32x4*)(alpha + j * 256 + o);
    f32x4 be = *(const f32x4*)(beta + j * 256 + o);
    f32x4 y;
#pragma unroll
    for (int k = 0; k < 4; ++k)
      y[k] = al[k] * (v[j][k] - mean) * rden + be[k];
    if (outf) *(f32x4*)(outf + base + j * 256 + o) = y;
    if (outb) {
      u32x2 w;
      w[0] = pk_bf16(y[0], y[1]);
      w[1] = pk_bf16(y[2], y[3]);
      *(u32x2*)(outb + base + j * 256 + o) = w;
    }
  }
}

// ---------------- launch ----------------

extern "C" void kernel_launch(void* const* d_in, const int* in_sizes, int n_in,
                              void* d_out, int out_size, void* d_ws, size_t ws_size,
                              hipStream_t stream) {
  (void)in_sizes; (void)n_in; (void)out_size; (void)ws_size;
  const float* x    = (const float*)d_in[0];
  const int*   mask = (const int*)d_in[1];
  const float* wq   = (const float*)d_in[2];
  const float* wk   = (const float*)d_in[3];
  const float* wv   = (const float*)d_in[4];
  const float* wo   = (const float*)d_in[5];
  const float* w1   = (const float*)d_in[6];
  const float* b1   = (const float*)d_in[7];
  const float* w2   = (const float*)d_in[8];
  const float* b2   = (const float*)d_in[9];
  const float* ln1a = (const float*)d_in[10];
  const float* ln1b = (const float*)d_in[11];
  const float* ln2a = (const float*)d_in[12];
  const float* ln2b = (const float*)d_in[13];
  float* out = (float*)d_out;

  char* ws = (char*)d_ws;
  size_t off = 0;
  auto alloc = [&](size_t bytes) -> void* {
    void* p = ws + off;
    off += (bytes + 255) & ~(size_t)255;
    return p;
  };
  u16* xb    = (u16*)alloc((size_t)BS * Dn * 2);      // reused as ctx later
  u16* wqkvT = (u16*)alloc((size_t)2304 * Dn * 2);
  u16* woT   = (u16*)alloc((size_t)Dn * Dn * 2);      // contiguous after wqkvT
  u16* w1T   = (u16*)alloc((size_t)DFFn * Dn * 2);
  u16* w2T   = (u16*)alloc((size_t)Dn * DFFn * 2);
  u16* qkv   = (u16*)alloc((size_t)BS * 2304 * 2);
  u16* vt    = (u16*)alloc((size_t)48 * 64 * Sn * 2);
  u16* x1b   = (u16*)alloc((size_t)BS * Dn * 2);
  u16* ff1   = (u16*)alloc((size_t)BS * DFFn * 2);
  u16* ctx   = xb;

  dim3 blk256(256), blk512(512);
  dim3 wblk(32, 8);
  cvt_x_kernel<<<dim3(BS * Dn / 8 / 256), blk256, 0, stream>>>(x, xb);
  wtrans4_kernel<<<dim3(24, 24, 4), wblk, 0, stream>>>(wq, wk, wv, wo, wqkvT);
  wtrans_kernel<<<dim3(96, 24), wblk, 0, stream>>>(w1, w1T, Dn, DFFn);
  wtrans_kernel<<<dim3(24, 96), wblk, 0, stream>>>(w2, w2T, DFFn, Dn);

  // qkv = xb @ [wq'|wk|wv]; V tiles fused-transposed into vt
  gemm_kernel<256, true, false, false, true><<<dim3(576), blk512, 0, stream>>>(xb, wqkvT, nullptr, qkv, 2304, 768, 18, vt);
  attn_kernel<<<dim3(768), blk256, 0, stream>>>(qkv, vt, mask, ctx);
  // attn_out = ctx @ wo   (into d_out as scratch)
  gemm_kernel<128, false, false, false, false><<<dim3(384), blk256, 0, stream>>>(ctx, woT, nullptr, out, 768, 768, 6, nullptr);
  // x1 = LN(x + attn_out): bf16 only
  ln_kernel<false><<<dim3(BS / 4), blk256, 0, stream>>>(x, out, ln1a, ln1b, nullptr, x1b);
  // ff1 = relu(x1 @ w1 + b1)
  gemm_kernel<256, true, true, true, false><<<dim3(768), blk512, 0, stream>>>(x1b, w1T, b1, ff1, 3072, 768, 24, nullptr);
  // ff2 = ff1 @ w2 + b2   (into d_out)
  gemm_kernel<128, false, false, true, false><<<dim3(384), blk256, 0, stream>>>(ff1, w2T, b2, out, 768, 3072, 6, nullptr);
  // out = LN(x1(bf16) + ff2)
  ln_kernel<true><<<dim3(BS / 4), blk256, 0, stream>>>(out, x1b, ln2a, ln2b, out, nullptr);
}

// Round 9
// 268.637 us; speedup vs baseline: 1.1827x; 1.0180x over previous
//
#include <hip/hip_runtime.h>
#include <stdint.h>

#define DEV __device__ __forceinline__

typedef uint16_t u16;
typedef __attribute__((ext_vector_type(8))) short short8;
typedef __attribute__((ext_vector_type(4))) float f32x4;
typedef __attribute__((ext_vector_type(8))) __bf16 bf16x8;
typedef __attribute__((ext_vector_type(4))) int int4v;
typedef __attribute__((ext_vector_type(2))) unsigned int u32x2;
typedef __attribute__((ext_vector_type(4))) short s16x4;

static constexpr int Bn = 4, Sn = 2048, Dn = 768, Hn = 12, DFFn = 3072;
static constexpr int BS = Bn * Sn;   // 8192 tokens
static constexpr float EPS = 1e-6f;
static constexpr float C1 = 0.18033688011112042f;   // 0.125 * log2(e)
static constexpr float SHIFT = 11.541560327111707f; // 8 * log2(e)

DEV u16 f2bf(float f) {
  union { float f; uint32_t u; } cv; cv.f = f;
  uint32_t u = cv.u;
  u += 0x7FFFu + ((u >> 16) & 1u);   // round-to-nearest-even
  return (u16)(u >> 16);
}

DEV uint32_t pk_bf16(float a, float b) {
  union { __bf16 h[2]; uint32_t u; } cv;
  cv.h[0] = (__bf16)a; cv.h[1] = (__bf16)b;
  return cv.u;
}

DEV float exp2_raw(float x) {
  float r;
  asm("v_exp_f32 %0, %1" : "=v"(r) : "v"(x));
  return r;
}

DEV float bf2f(u16 v) {
  union { uint32_t u; float f; } cv; cv.u = (uint32_t)v << 16;
  return cv.f;
}

DEV f32x4 mfma16(short8 a, short8 b, f32x4 c) {
  return __builtin_amdgcn_mfma_f32_16x16x32_bf16(
      __builtin_bit_cast(bf16x8, a), __builtin_bit_cast(bf16x8, b), c, 0, 0, 0);
}

DEV void glds16(const void* g, void* l) {
  __builtin_amdgcn_global_load_lds(
      (const __attribute__((address_space(1))) void*)g,
      (__attribute__((address_space(3))) void*)l, 16, 0, 0);
}

DEV void barf() {
  asm volatile("" ::: "memory");
  __builtin_amdgcn_s_barrier();
  asm volatile("" ::: "memory");
}
#define WAITV(n) asm volatile("s_waitcnt vmcnt(" #n ")" ::: "memory")

// inverse of slot u = (r*4 + s) ^ (r&7); valid for r < 256
DEV void inv_swz(int u, int& r, int& s) {
  r = ((u >> 2) & 0x1FE) | (((u >> 2) ^ (u >> 4)) & 1);
  s = ((u ^ (u >> 2) ^ (u >> 4)) & 1) | ((u ^ (u >> 2)) & 2);
}

// ---------------- converts / transposes ----------------

__global__ void cvt_x_kernel(const float* __restrict__ in, u16* __restrict__ out) {
  size_t i = (size_t)blockIdx.x * 256 + threadIdx.x;
  const f32x4* p = (const f32x4*)in + i * 2;
  f32x4 a = p[0], b = p[1];
  short8 o;
  o[0] = (short)f2bf(a[0]); o[1] = (short)f2bf(a[1]);
  o[2] = (short)f2bf(a[2]); o[3] = (short)f2bf(a[3]);
  o[4] = (short)f2bf(b[0]); o[5] = (short)f2bf(b[1]);
  o[6] = (short)f2bf(b[2]); o[7] = (short)f2bf(b[3]);
  *(short8*)(out + i * 8) = o;
}

// four 768x768 weights [K][N] fp32 -> out[z][N][K] bf16 (z=0 scaled by C1)
__global__ void wtrans4_kernel(const float* __restrict__ w0, const float* __restrict__ w1,
                               const float* __restrict__ w2, const float* __restrict__ w3,
                               u16* __restrict__ out) {
  __shared__ float T[32][33];
  const int z = blockIdx.z;
  const float* w = (z == 0) ? w0 : (z == 1) ? w1 : (z == 2) ? w2 : w3;
  const float scale = (z == 0) ? C1 : 1.f;
  u16* o = out + (size_t)z * Dn * Dn;
  int tx = threadIdx.x, ty = threadIdx.y;
  int n0 = blockIdx.x * 32, k0 = blockIdx.y * 32;
#pragma unroll
  for (int i = 0; i < 4; ++i)
    T[ty + 8 * i][tx] = w[(size_t)(k0 + ty + 8 * i) * Dn + n0 + tx];
  __syncthreads();
#pragma unroll
  for (int i = 0; i < 4; ++i)
    o[(size_t)(n0 + ty + 8 * i) * Dn + k0 + tx] = f2bf(T[tx][ty + 8 * i] * scale);
}

// w[K][N] fp32 -> out[N][K] bf16
__global__ void wtrans_kernel(const float* __restrict__ w, u16* __restrict__ out,
                              int K, int N) {
  __shared__ float T[32][33];
  int tx = threadIdx.x, ty = threadIdx.y;
  int n0 = blockIdx.x * 32, k0 = blockIdx.y * 32;
#pragma unroll
  for (int i = 0; i < 4; ++i)
    T[ty + 8 * i][tx] = w[(size_t)(k0 + ty + 8 * i) * N + n0 + tx];
  __syncthreads();
#pragma unroll
  for (int i = 0; i < 4; ++i)
    out[(size_t)(n0 + ty + 8 * i) * K + k0 + tx] = f2bf(T[tx][ty + 8 * i]);
}

// ==== GEMM BMx128, BK=32, depth-2 prefetch (3 LDS buffers), 1 barrier/tile ===
// C[M][N] = A[M][K] * Bt[N][K]^T.  XCD-aware block decode.
// VFUSE: qkv V tiles (col0 >= 1536) written transposed to vt[bh][dk][S].
// RES: 0 none, 1 add fp32 residual, 2 add bf16 residual (element [row][col]).

template<int BM, bool OUT_BF16, bool RELU, bool HAS_BIAS, bool VFUSE, int RES>
__global__ __launch_bounds__(BM * 2, 4)
void gemm_kernel(const u16* __restrict__ A, const u16* __restrict__ Bt,
                 const float* __restrict__ bias, void* __restrict__ Cout,
                 int N, int K, int gx, u16* __restrict__ vt,
                 const void* __restrict__ resid) {
  constexpr int ABYTES = BM * 64;          // A bytes per buffer (BM x 32 bf16)
  constexpr int BUFSZ = ABYTES + 8192;     // + B (128 x 32 bf16)
  __shared__ char lds[3 * BUFSZ];
  const int tid = threadIdx.x;
  const int wave = tid >> 6, lane = tid & 63;
  const int lr = lane & 15, lg = lane >> 4;
  const int wr = wave >> 1, wc = wave & 1;

  const int kk = blockIdx.x >> 3, xcd = blockIdx.x & 7;
  const int row0 = (xcd + 8 * (kk / gx)) * BM, col0 = (kk % gx) * 128;

  size_t aofs[2], bofs[2];
#pragma unroll
  for (int i = 0; i < 2; ++i) {
    int r, s;
    inv_swz(tid + i * (BM * 2), r, s);
    aofs[i] = (size_t)(row0 + r) * K + s * 8;
  }
  {
    int r, s;
    inv_swz(tid, r, s);
    bofs[0] = (size_t)(col0 + r) * K + s * 8;
    if (BM == 128) {
      inv_swz(tid + 256, r, s);
      bofs[1] = (size_t)(col0 + r) * K + s * 8;
    }
  }
  const int aD0 = wave * 1024, aD1 = BM * 32 + wave * 1024;

  int aB[4], bB[4];
#pragma unroll
  for (int mi = 0; mi < 4; ++mi) {
    int row = wr * 64 + mi * 16 + lr;
    aB[mi] = ((row << 6) | (lg << 4)) ^ ((row & 7) << 4);
  }
#pragma unroll
  for (int nj = 0; nj < 4; ++nj) {
    int row = wc * 64 + nj * 16 + lr;
    bB[nj] = ((row << 6) | (lg << 4)) ^ ((row & 7) << 4);
  }

  f32x4 acc[4][4];
#pragma unroll
  for (int i = 0; i < 4; ++i)
#pragma unroll
    for (int j = 0; j < 4; ++j) acc[i][j] = (f32x4){0.f, 0.f, 0.f, 0.f};

  const int NT = K >> 5;
  auto stage = [&](char* buf, int kb) {
    glds16(A + aofs[0] + kb, buf + aD0);
    glds16(A + aofs[1] + kb, buf + aD1);
    glds16(Bt + bofs[0] + kb, buf + ABYTES + wave * 1024);
    if (BM == 128)
      glds16(Bt + bofs[1] + kb, buf + ABYTES + 4096 + wave * 1024);
  };

  char* b0 = lds;              // read target (tile t)
  char* b1 = lds + BUFSZ;      // tile t+1 in flight
  char* b2 = lds + 2 * BUFSZ;  // stage target (tile t+2)
  stage(b0, 0);
  stage(b1, 32);
  for (int t = 0; t < NT; ++t) {
    if (t < NT - 1) {
      if (BM == 256) WAITV(3); else WAITV(4);
    } else {
      WAITV(0);
    }
    barf();
    if (t + 2 < NT) stage(b2, (t + 2) * 32);
    short8 a_[4], b_[4];
#pragma unroll
    for (int mi = 0; mi < 4; ++mi)
      a_[mi] = *(const short8*)(b0 + aB[mi]);
#pragma unroll
    for (int nj = 0; nj < 4; ++nj)
      b_[nj] = *(const short8*)(b0 + ABYTES + bB[nj]);
    __builtin_amdgcn_s_setprio(1);
#pragma unroll
    for (int mi = 0; mi < 4; ++mi)
#pragma unroll
      for (int nj = 0; nj < 4; ++nj)
        acc[mi][nj] = mfma16(a_[mi], b_[nj], acc[mi][nj]);
    __builtin_amdgcn_s_setprio(0);
    char* tmp = b0; b0 = b1; b1 = b2; b2 = tmp;
  }

  if (VFUSE && col0 >= 1536) {
    // V tile: write to vt[bh = b*12 + (col-1536)/64][dk = col%64][s = row%2048]
#pragma unroll
    for (int mi = 0; mi < 4; ++mi) {
      int row = row0 + wr * 64 + mi * 16 + lg * 4;
      int b = row >> 11, s = row & 2047;
#pragma unroll
      for (int nj = 0; nj < 4; ++nj) {
        int col = col0 + wc * 64 + nj * 16 + lr;
        int bh = b * Hn + ((col - 1536) >> 6), dk = col & 63;
        s16x4 v;
#pragma unroll
        for (int r = 0; r < 4; ++r) v[r] = (short)f2bf(acc[mi][nj][r]);
        *(s16x4*)(vt + (size_t)(bh * 64 + dk) * Sn + s) = v;
      }
    }
    return;
  }

#pragma unroll
  for (int mi = 0; mi < 4; ++mi) {
    int row = row0 + wr * 64 + mi * 16 + lg * 4;
#pragma unroll
    for (int nj = 0; nj < 4; ++nj) {
      int col = col0 + wc * 64 + nj * 16 + lr;
      float bv = HAS_BIAS ? bias[col] : 0.f;
#pragma unroll
      for (int r = 0; r < 4; ++r) {
        float v = acc[mi][nj][r] + bv;
        size_t o = (size_t)(row + r) * N + col;
        if (RES == 1) v += ((const float*)resid)[o];
        if (RES == 2) v += bf2f(((const u16*)resid)[o]);
        if (RELU) v = fmaxf(v, 0.f);
        if (OUT_BF16) ((u16*)Cout)[o] = f2bf(v);
        else ((float*)Cout)[o] = v;
      }
    }
  }
}

// ---------------- flash attention v6 ----------------
// 128 q-rows/block; static-shift softmax; K/V fragments read ONCE per tile
// (interleaved per-f with both q-sets' MFMAs -- no bulk hoist, no spill).

__global__ __launch_bounds__(256, 3)
void attn_kernel(const u16* __restrict__ qkv, const u16* __restrict__ vt,
                 const int* __restrict__ mask, u16* __restrict__ ctx) {
  __shared__ u16 kbuf[2][4096];
  __shared__ u16 vbuf[2][4096];
  __shared__ u16 pbuf[4][2][1024];

  const int tid = threadIdx.x;
  const int wave = tid >> 6, lane = tid & 63;
  const int lr = lane & 15, lg = lane >> 4;

  const int lin = blockIdx.x;
  const int logical = (lin & 7) * 96 + (lin >> 3);
  const int qt = logical & 15;
  const int bh = logical >> 4;
  const int b = bh / Hn, h = bh % Hn;

  int ok;
  {
    const int4v* ms = (const int4v*)(mask + b * Sn);
    int4v m0 = ms[tid * 2], m1 = ms[tid * 2 + 1];
    ok = m0[0] && m0[1] && m0[2] && m0[3] && m1[0] && m1[1] && m1[2] && m1[3];
  }
  const bool allones = (__syncthreads_and(ok) != 0);

  const int cu = (lane & 7) ^ (lane >> 3);
  const int r0 = wave * 16 + (lane >> 3);
  const u16* kg0 = qkv + (size_t)(b * Sn + r0) * 2304 + 768 + h * 64 + cu * 8;
  const u16* vg0 = vt + (size_t)(bh * 64 + r0) * Sn + cu * 8;
  u16* kd = &kbuf[0][0] + wave * 1024;
  u16* vd = &vbuf[0][0] + wave * 1024;

  const size_t qrowA = (size_t)(b * Sn + qt * 128 + wave * 16 + lr) * 2304 + h * 64 + lg * 8;
  short8 qa0 = *(const short8*)(qkv + qrowA);
  short8 qa1 = *(const short8*)(qkv + qrowA + 32);
  const size_t qrowB = qrowA + (size_t)64 * 2304;
  short8 qb0 = *(const short8*)(qkv + qrowB);
  short8 qb1 = *(const short8*)(qkv + qrowB + 32);

  const int rlo = (lg ^ (lr & 7)) << 4;
  const int rhi = ((4 + lg) ^ (lr & 7)) << 4;
  const int rowb = lr * 128;

  f32x4 caccA[4], caccB[4];
#pragma unroll
  for (int i = 0; i < 4; ++i) {
    caccA[i] = (f32x4){0.f, 0.f, 0.f, 0.f};
    caccB[i] = (f32x4){0.f, 0.f, 0.f, 0.f};
  }
  float lsA = 0.f, lsB = 0.f;

  u16* pwA = &pbuf[wave][0][0];
  u16* pwB = &pbuf[wave][1][0];
  const int pwr = (lg >> 1), pwo = 8 * (lg & 1);

  auto stage = [&](int bf, int c) {
    const u16* kg = kg0 + (size_t)c * 64 * 2304;
    const u16* vg = vg0 + c * 64;
    glds16(kg,            kd + bf * 4096);
    glds16(kg + 8 * 2304, kd + bf * 4096 + 512);
    glds16(vg,            vd + bf * 4096);
    glds16(vg + 8 * Sn,   vd + bf * 4096 + 512);
  };

  stage(0, 0);
  __syncthreads();
  int cur = 0;
  for (int c = 0; c < 32; ++c) {
    if (c + 1 < 32) stage(cur ^ 1, c + 1);
    const char* kb = (const char*)&kbuf[cur][0];
    const char* vb = (const char*)&vbuf[cur][0];

    int4v mk[4];
    if (!allones) {
      const int4v* mp = (const int4v*)(mask + b * Sn + c * 64 + lg * 4);
#pragma unroll
      for (int f = 0; f < 4; ++f) mk[f] = mp[f * 4];
    }

    // QK^T both q-sets, each K fragment read once
    f32x4 scA[4], scB[4];
#pragma unroll
    for (int f = 0; f < 4; ++f) {
      short8 k0 = *(const short8*)(kb + f * 2048 + rowb + rlo);
      short8 k1 = *(const short8*)(kb + f * 2048 + rowb + rhi);
      f32x4 zA = (f32x4){-SHIFT, -SHIFT, -SHIFT, -SHIFT};
      zA = mfma16(k0, qa0, zA);
      zA = mfma16(k1, qa1, zA);
      scA[f] = zA;
      f32x4 zB = (f32x4){-SHIFT, -SHIFT, -SHIFT, -SHIFT};
      zB = mfma16(k0, qb0, zB);
      zB = mfma16(k1, qb1, zB);
      scB[f] = zB;
    }
    if (!allones) {
#pragma unroll
      for (int f = 0; f < 4; ++f)
#pragma unroll
        for (int r = 0; r < 4; ++r) {
          scA[f][r] = mk[f][r] ? scA[f][r] : -1.0e5f;
          scB[f][r] = mk[f][r] ? scB[f][r] : -1.0e5f;
        }
    }
#pragma unroll
    for (int f = 0; f < 4; ++f) {
#pragma unroll
      for (int r = 0; r < 4; ++r) {
        float pA = exp2_raw(scA[f][r]);
        scA[f][r] = pA;
        lsA += pA;
        float pB = exp2_raw(scB[f][r]);
        scB[f][r] = pB;
        lsB += pB;
      }
    }
    // P -> bf16 -> per-wave swizzled LDS (both sets), then read fragments
#pragma unroll
    for (int f = 0; f < 4; ++f) {
      u32x2 wA, wB;
      wA[0] = pk_bf16(scA[f][0], scA[f][1]);
      wA[1] = pk_bf16(scA[f][2], scA[f][3]);
      wB[0] = pk_bf16(scB[f][0], scB[f][1]);
      wB[1] = pk_bf16(scB[f][2], scB[f][3]);
      const int po = rowb + (((2 * f + pwr) ^ (lr & 7)) << 4) + pwo;
      *(u32x2*)((char*)pwA + po) = wA;
      *(u32x2*)((char*)pwB + po) = wB;
    }
    short8 pfA0 = *(const short8*)((const char*)pwA + rowb + rlo);
    short8 pfA1 = *(const short8*)((const char*)pwA + rowb + rhi);
    short8 pfB0 = *(const short8*)((const char*)pwB + rowb + rlo);
    short8 pfB1 = *(const short8*)((const char*)pwB + rowb + rhi);

    // PV both q-sets, each V fragment read once
#pragma unroll
    for (int fd = 0; fd < 4; ++fd) {
      short8 v0 = *(const short8*)(vb + fd * 2048 + rowb + rlo);
      short8 v1 = *(const short8*)(vb + fd * 2048 + rowb + rhi);
      caccA[fd] = mfma16(pfA0, v0, caccA[fd]);
      caccA[fd] = mfma16(pfA1, v1, caccA[fd]);
      caccB[fd] = mfma16(pfB0, v0, caccB[fd]);
      caccB[fd] = mfma16(pfB1, v1, caccB[fd]);
    }
    __syncthreads();
    cur ^= 1;
  }

  lsA += __shfl_xor(lsA, 16, 64); lsA += __shfl_xor(lsA, 32, 64);
  lsB += __shfl_xor(lsB, 16, 64); lsB += __shfl_xor(lsB, 32, 64);
  float linvA[4], linvB[4];
#pragma unroll
  for (int r = 0; r < 4; ++r) {
    linvA[r] = 1.0f / __shfl(lsA, lg * 4 + r, 64);
    linvB[r] = 1.0f / __shfl(lsB, lg * 4 + r, 64);
  }
  const int orow = b * Sn + qt * 128 + wave * 16 + lg * 4;
#pragma unroll
  for (int fd = 0; fd < 4; ++fd) {
    int col = h * 64 + fd * 16 + lr;
#pragma unroll
    for (int r = 0; r < 4; ++r) {
      ctx[(size_t)(orow + r) * Dn + col] = f2bf(caccA[fd][r] * linvA[r]);
      ctx[(size_t)(orow + 64 + r) * Dn + col] = f2bf(caccB[fd][r] * linvB[r]);
    }
  }
}

// ---- LayerNorm: one wave per row; input = a (+ optional bsrc) --------------
// BSRC: 0 = none (a already contains the residual sum), 1 = fp32, 2 = bf16

template<int BSRC>
__global__ __launch_bounds__(256)
void ln_kernel(const float* __restrict__ a, const void* __restrict__ bsrc,
               const float* __restrict__ alpha, const float* __restrict__ beta,
               float* __restrict__ outf, u16* __restrict__ outb) {
  const int wave = threadIdx.x >> 6, lane = threadIdx.x & 63;
  const size_t base = ((size_t)blockIdx.x * 4 + wave) * Dn;
  const int o = lane * 4;
  f32x4 v[3];
  float s = 0.f, q = 0.f;
#pragma unroll
  for (int j = 0; j < 3; ++j) {
    f32x4 x = *(const f32x4*)(a + base + j * 256 + o);
    if (BSRC == 1) {
      f32x4 bv = *(const f32x4*)((const float*)bsrc + base + j * 256 + o);
      x = x + bv;
    } else if (BSRC == 2) {
      s16x4 bb = *(const s16x4*)((const u16*)bsrc + base + j * 256 + o);
#pragma unroll
      for (int k = 0; k < 4; ++k) x[k] += bf2f((u16)bb[k]);
    }
    v[j] = x;
    s += (x[0] + x[1]) + (x[2] + x[3]);
    q += (x[0] * x[0] + x[1] * x[1]) + (x[2] * x[2] + x[3] * x[3]);
  }
#pragma unroll
  for (int sh = 1; sh < 64; sh <<= 1) {
    s += __shfl_xor(s, sh, 64);
    q += __shfl_xor(q, sh, 64);
  }
  const float mean = s * (1.f / 768.f);
  float var = (q - 768.f * mean * mean) * (1.f / 767.f);
  var = fmaxf(var, 0.f);
  const float rden = 1.f / (sqrtf(var) + EPS);
#pragma unroll
  for (int j = 0; j < 3; ++j) {
    f32x4 al = *(const f32x4*)(alpha + j * 256 + o);
    f32x4 be = *(const f32x4*)(beta + j * 256 + o);
    f32x4 y;
#pragma unroll
    for (int k = 0; k < 4; ++k)
      y[k] = al[k] * (v[j][k] - mean) * rden + be[k];
    if (outf) *(f32x4*)(outf + base + j * 256 + o) = y;
    if (outb) {
      u32x2 w;
      w[0] = pk_bf16(y[0], y[1]);
      w[1] = pk_bf16(y[2], y[3]);
      *(u32x2*)(outb + base + j * 256 + o) = w;
    }
  }
}

// ---------------- launch ----------------

extern "C" void kernel_launch(void* const* d_in, const int* in_sizes, int n_in,
                              void* d_out, int out_size, void* d_ws, size_t ws_size,
                              hipStream_t stream) {
  (void)in_sizes; (void)n_in; (void)out_size; (void)ws_size;
  const float* x    = (const float*)d_in[0];
  const int*   mask = (const int*)d_in[1];
  const float* wq   = (const float*)d_in[2];
  const float* wk   = (const float*)d_in[3];
  const float* wv   = (const float*)d_in[4];
  const float* wo   = (const float*)d_in[5];
  const float* w1   = (const float*)d_in[6];
  const float* b1   = (const float*)d_in[7];
  const float* w2   = (const float*)d_in[8];
  const float* b2   = (const float*)d_in[9];
  const float* ln1a = (const float*)d_in[10];
  const float* ln1b = (const float*)d_in[11];
  const float* ln2a = (const float*)d_in[12];
  const float* ln2b = (const float*)d_in[13];
  float* out = (float*)d_out;

  char* ws = (char*)d_ws;
  size_t off = 0;
  auto alloc = [&](size_t bytes) -> void* {
    void* p = ws + off;
    off += (bytes + 255) & ~(size_t)255;
    return p;
  };
  u16* xb    = (u16*)alloc((size_t)BS * Dn * 2);      // reused as ctx later
  u16* wqkvT = (u16*)alloc((size_t)2304 * Dn * 2);
  u16* woT   = (u16*)alloc((size_t)Dn * Dn * 2);      // contiguous after wqkvT
  u16* w1T   = (u16*)alloc((size_t)DFFn * Dn * 2);
  u16* w2T   = (u16*)alloc((size_t)Dn * DFFn * 2);
  u16* qkv   = (u16*)alloc((size_t)BS * 2304 * 2);
  u16* vt    = (u16*)alloc((size_t)48 * 64 * Sn * 2);
  u16* x1b   = (u16*)alloc((size_t)BS * Dn * 2);
  u16* ff1   = (u16*)alloc((size_t)BS * DFFn * 2);
  u16* ctx   = xb;

  dim3 blk256(256), blk512(512);
  dim3 wblk(32, 8);
  cvt_x_kernel<<<dim3(BS * Dn / 8 / 256), blk256, 0, stream>>>(x, xb);
  wtrans4_kernel<<<dim3(24, 24, 4), wblk, 0, stream>>>(wq, wk, wv, wo, wqkvT);
  wtrans_kernel<<<dim3(96, 24), wblk, 0, stream>>>(w1, w1T, Dn, DFFn);
  wtrans_kernel<<<dim3(24, 96), wblk, 0, stream>>>(w2, w2T, DFFn, Dn);

  // qkv = xb @ [wq'|wk|wv]; V tiles fused-transposed into vt
  gemm_kernel<256, true, false, false, true, 0><<<dim3(576), blk512, 0, stream>>>(xb, wqkvT, nullptr, qkv, 2304, 768, 18, vt, nullptr);
  attn_kernel<<<dim3(768), blk256, 0, stream>>>(qkv, vt, mask, ctx);
  // out = ctx @ wo + x   (residual fused)
  gemm_kernel<128, false, false, false, false, 1><<<dim3(384), blk256, 0, stream>>>(ctx, woT, nullptr, out, 768, 768, 6, nullptr, x);
  // x1 = LN(out) -> bf16
  ln_kernel<0><<<dim3(BS / 4), blk256, 0, stream>>>(out, nullptr, ln1a, ln1b, nullptr, x1b);
  // ff1 = relu(x1 @ w1 + b1)
  gemm_kernel<256, true, true, true, false, 0><<<dim3(768), blk512, 0, stream>>>(x1b, w1T, b1, ff1, 3072, 768, 24, nullptr, nullptr);
  // out = ff1 @ w2 + b2 + x1   (residual fused)
  gemm_kernel<128, false, false, true, false, 2><<<dim3(384), blk256, 0, stream>>>(ff1, w2T, b2, out, 768, 3072, 6, nullptr, x1b);
  // out = LN(out)
  ln_kernel<0><<<dim3(BS / 4), blk256, 0, stream>>>(out, nullptr, ln2a, ln2b, out, nullptr);
}

// Round 10
// 261.427 us; speedup vs baseline: 1.2153x; 1.0276x over previous
//
#include <hip/hip_runtime.h>
#include <stdint.h>

#define DEV __device__ __forceinline__

typedef uint16_t u16;
typedef __attribute__((ext_vector_type(8))) short short8;
typedef __attribute__((ext_vector_type(4))) float f32x4;
typedef __attribute__((ext_vector_type(8))) __bf16 bf16x8;
typedef __attribute__((ext_vector_type(4))) int int4v;
typedef __attribute__((ext_vector_type(2))) unsigned int u32x2;
typedef __attribute__((ext_vector_type(4))) short s16x4;

static constexpr int Bn = 4, Sn = 2048, Dn = 768, Hn = 12, DFFn = 3072;
static constexpr int BS = Bn * Sn;   // 8192 tokens
static constexpr float EPS = 1e-6f;
static constexpr float C1 = 0.18033688011112042f;   // 0.125 * log2(e)
static constexpr float SHIFT = 11.541560327111707f; // 8 * log2(e)

DEV u16 f2bf(float f) {
  union { float f; uint32_t u; } cv; cv.f = f;
  uint32_t u = cv.u;
  u += 0x7FFFu + ((u >> 16) & 1u);   // round-to-nearest-even
  return (u16)(u >> 16);
}

DEV uint32_t pk_bf16(float a, float b) {
  union { __bf16 h[2]; uint32_t u; } cv;
  cv.h[0] = (__bf16)a; cv.h[1] = (__bf16)b;
  return cv.u;
}

DEV float exp2_raw(float x) {
  float r;
  asm("v_exp_f32 %0, %1" : "=v"(r) : "v"(x));
  return r;
}

DEV float bf2f(u16 v) {
  union { uint32_t u; float f; } cv; cv.u = (uint32_t)v << 16;
  return cv.f;
}

DEV f32x4 mfma16(short8 a, short8 b, f32x4 c) {
  return __builtin_amdgcn_mfma_f32_16x16x32_bf16(
      __builtin_bit_cast(bf16x8, a), __builtin_bit_cast(bf16x8, b), c, 0, 0, 0);
}

DEV void glds16(const void* g, void* l) {
  __builtin_amdgcn_global_load_lds(
      (const __attribute__((address_space(1))) void*)g,
      (__attribute__((address_space(3))) void*)l, 16, 0, 0);
}

DEV void barf() {
  asm volatile("" ::: "memory");
  __builtin_amdgcn_s_barrier();
  asm volatile("" ::: "memory");
}
#define WAITV(n) asm volatile("s_waitcnt vmcnt(" #n ")" ::: "memory")

// inverse of slot u = (r*4 + s) ^ (r&7); valid for r < 256
DEV void inv_swz(int u, int& r, int& s) {
  r = ((u >> 2) & 0x1FE) | (((u >> 2) ^ (u >> 4)) & 1);
  s = ((u ^ (u >> 2) ^ (u >> 4)) & 1) | ((u ^ (u >> 2)) & 2);
}

// ---------------- fused prep: x->bf16 + all weight transposes ----------------
// blocks [0,3072): cvt x; [3072,5376): wq/wk/wv/wo (z=q/576); [5376,7680): w1;
// [7680,9984): w2.

__global__ __launch_bounds__(256)
void prep_kernel(const float* __restrict__ x,
                 const float* __restrict__ wq, const float* __restrict__ wk,
                 const float* __restrict__ wv, const float* __restrict__ wo,
                 const float* __restrict__ w1, const float* __restrict__ w2,
                 u16* __restrict__ xb, u16* __restrict__ wqkvT,
                 u16* __restrict__ w1T, u16* __restrict__ w2T) {
  const int bid = blockIdx.x;
  const int tid = threadIdx.x;
  if (bid < 3072) {
    size_t i = (size_t)bid * 256 + tid;
    const f32x4* p = (const f32x4*)x + i * 2;
    f32x4 a = p[0], b = p[1];
    short8 o;
    o[0] = (short)f2bf(a[0]); o[1] = (short)f2bf(a[1]);
    o[2] = (short)f2bf(a[2]); o[3] = (short)f2bf(a[3]);
    o[4] = (short)f2bf(b[0]); o[5] = (short)f2bf(b[1]);
    o[6] = (short)f2bf(b[2]); o[7] = (short)f2bf(b[3]);
    *(short8*)(xb + i * 8) = o;
    return;
  }
  __shared__ float T[32][33];
  const float* w; u16* o; int K, N, bx, by;
  float scale = 1.f;
  if (bid < 5376) {
    int q = bid - 3072;
    int z = q / 576; q -= z * 576;
    w = (z == 0) ? wq : (z == 1) ? wk : (z == 2) ? wv : wo;
    o = wqkvT + (size_t)z * Dn * Dn;
    K = Dn; N = Dn;
    scale = (z == 0) ? C1 : 1.f;
    bx = q % 24; by = q / 24;
  } else if (bid < 7680) {
    int q = bid - 5376;
    w = w1; o = w1T; K = Dn; N = DFFn;
    bx = q % 96; by = q / 96;
  } else {
    int q = bid - 7680;
    w = w2; o = w2T; K = DFFn; N = Dn;
    bx = q % 24; by = q / 24;
  }
  const int tx = tid & 31, ty = tid >> 5;
  const int n0 = bx * 32, k0 = by * 32;
#pragma unroll
  for (int i = 0; i < 4; ++i)
    T[ty + 8 * i][tx] = w[(size_t)(k0 + ty + 8 * i) * N + n0 + tx];
  __syncthreads();
#pragma unroll
  for (int i = 0; i < 4; ++i)
    o[(size_t)(n0 + ty + 8 * i) * K + k0 + tx] = f2bf(T[tx][ty + 8 * i] * scale);
}

// ==== GEMM BMx128, BK=32, depth-2 prefetch (3 LDS buffers), 1 barrier/tile ===
// C[M][N] = A[M][K] * Bt[N][K]^T.  XCD-aware block decode.
// VFUSE: qkv V tiles (col0 >= 1536) written transposed to vt[bh][dk][S].
// RES: 0 none, 1 add fp32 residual, 2 add bf16 residual (element [row][col]).

template<int BM, bool OUT_BF16, bool RELU, bool HAS_BIAS, bool VFUSE, int RES>
__global__ __launch_bounds__(BM * 2, 4)
void gemm_kernel(const u16* __restrict__ A, const u16* __restrict__ Bt,
                 const float* __restrict__ bias, void* __restrict__ Cout,
                 int N, int K, int gx, u16* __restrict__ vt,
                 const void* __restrict__ resid) {
  constexpr int ABYTES = BM * 64;          // A bytes per buffer (BM x 32 bf16)
  constexpr int BUFSZ = ABYTES + 8192;     // + B (128 x 32 bf16)
  __shared__ char lds[3 * BUFSZ];
  const int tid = threadIdx.x;
  const int wave = tid >> 6, lane = tid & 63;
  const int lr = lane & 15, lg = lane >> 4;
  const int wr = wave >> 1, wc = wave & 1;

  const int kk = blockIdx.x >> 3, xcd = blockIdx.x & 7;
  const int row0 = (xcd + 8 * (kk / gx)) * BM, col0 = (kk % gx) * 128;

  size_t aofs[2], bofs[2];
#pragma unroll
  for (int i = 0; i < 2; ++i) {
    int r, s;
    inv_swz(tid + i * (BM * 2), r, s);
    aofs[i] = (size_t)(row0 + r) * K + s * 8;
  }
  {
    int r, s;
    inv_swz(tid, r, s);
    bofs[0] = (size_t)(col0 + r) * K + s * 8;
    if (BM == 128) {
      inv_swz(tid + 256, r, s);
      bofs[1] = (size_t)(col0 + r) * K + s * 8;
    }
  }
  const int aD0 = wave * 1024, aD1 = BM * 32 + wave * 1024;

  int aB[4], bB[4];
#pragma unroll
  for (int mi = 0; mi < 4; ++mi) {
    int row = wr * 64 + mi * 16 + lr;
    aB[mi] = ((row << 6) | (lg << 4)) ^ ((row & 7) << 4);
  }
#pragma unroll
  for (int nj = 0; nj < 4; ++nj) {
    int row = wc * 64 + nj * 16 + lr;
    bB[nj] = ((row << 6) | (lg << 4)) ^ ((row & 7) << 4);
  }

  f32x4 acc[4][4];
#pragma unroll
  for (int i = 0; i < 4; ++i)
#pragma unroll
    for (int j = 0; j < 4; ++j) acc[i][j] = (f32x4){0.f, 0.f, 0.f, 0.f};

  const int NT = K >> 5;
  auto stage = [&](char* buf, int kb) {
    glds16(A + aofs[0] + kb, buf + aD0);
    glds16(A + aofs[1] + kb, buf + aD1);
    glds16(Bt + bofs[0] + kb, buf + ABYTES + wave * 1024);
    if (BM == 128)
      glds16(Bt + bofs[1] + kb, buf + ABYTES + 4096 + wave * 1024);
  };

  char* b0 = lds;              // read target (tile t)
  char* b1 = lds + BUFSZ;      // tile t+1 in flight
  char* b2 = lds + 2 * BUFSZ;  // stage target (tile t+2)
  stage(b0, 0);
  stage(b1, 32);
  for (int t = 0; t < NT; ++t) {
    if (t < NT - 1) {
      if (BM == 256) WAITV(3); else WAITV(4);
    } else {
      WAITV(0);
    }
    barf();
    if (t + 2 < NT) stage(b2, (t + 2) * 32);
    short8 a_[4], b_[4];
#pragma unroll
    for (int mi = 0; mi < 4; ++mi)
      a_[mi] = *(const short8*)(b0 + aB[mi]);
#pragma unroll
    for (int nj = 0; nj < 4; ++nj)
      b_[nj] = *(const short8*)(b0 + ABYTES + bB[nj]);
    __builtin_amdgcn_s_setprio(1);
#pragma unroll
    for (int mi = 0; mi < 4; ++mi)
#pragma unroll
      for (int nj = 0; nj < 4; ++nj)
        acc[mi][nj] = mfma16(a_[mi], b_[nj], acc[mi][nj]);
    __builtin_amdgcn_s_setprio(0);
    char* tmp = b0; b0 = b1; b1 = b2; b2 = tmp;
  }

  if (VFUSE && col0 >= 1536) {
    // V tile: write to vt[bh = b*12 + (col-1536)/64][dk = col%64][s = row%2048]
#pragma unroll
    for (int mi = 0; mi < 4; ++mi) {
      int row = row0 + wr * 64 + mi * 16 + lg * 4;
      int b = row >> 11, s = row & 2047;
#pragma unroll
      for (int nj = 0; nj < 4; ++nj) {
        int col = col0 + wc * 64 + nj * 16 + lr;
        int bh = b * Hn + ((col - 1536) >> 6), dk = col & 63;
        s16x4 v;
#pragma unroll
        for (int r = 0; r < 4; ++r) v[r] = (short)f2bf(acc[mi][nj][r]);
        *(s16x4*)(vt + (size_t)(bh * 64 + dk) * Sn + s) = v;
      }
    }
    return;
  }

#pragma unroll
  for (int mi = 0; mi < 4; ++mi) {
    int row = row0 + wr * 64 + mi * 16 + lg * 4;
#pragma unroll
    for (int nj = 0; nj < 4; ++nj) {
      int col = col0 + wc * 64 + nj * 16 + lr;
      float bv = HAS_BIAS ? bias[col] : 0.f;
#pragma unroll
      for (int r = 0; r < 4; ++r) {
        float v = acc[mi][nj][r] + bv;
        size_t o = (size_t)(row + r) * N + col;
        if (RES == 1) v += ((const float*)resid)[o];
        if (RES == 2) v += bf2f(((const u16*)resid)[o]);
        if (RELU) v = fmaxf(v, 0.f);
        if (OUT_BF16) ((u16*)Cout)[o] = f2bf(v);
        else ((float*)Cout)[o] = v;
      }
    }
  }
}

// ---------------- flash attention v7 ----------------
// 128 q-rows/block; static-shift softmax; K/V fragments read once per tile;
// softmax denominator l computed on the MATRIX pipe: extra MFMA of the bf16
// P fragments against an all-ones B-operand accumulates l[q] directly in the
// PV accumulator layout (no VALU adds, no end-of-loop shuffles), and makes
// numerator/denominator use identical bf16-rounded P.

__global__ __launch_bounds__(256, 3)
void attn_kernel(const u16* __restrict__ qkv, const u16* __restrict__ vt,
                 const int* __restrict__ mask, u16* __restrict__ ctx) {
  __shared__ u16 kbuf[2][4096];
  __shared__ u16 vbuf[2][4096];
  __shared__ u16 pbuf[4][2][1024];

  const int tid = threadIdx.x;
  const int wave = tid >> 6, lane = tid & 63;
  const int lr = lane & 15, lg = lane >> 4;

  const int lin = blockIdx.x;
  const int logical = (lin & 7) * 96 + (lin >> 3);
  const int qt = logical & 15;
  const int bh = logical >> 4;
  const int b = bh / Hn, h = bh % Hn;

  int ok;
  {
    const int4v* ms = (const int4v*)(mask + b * Sn);
    int4v m0 = ms[tid * 2], m1 = ms[tid * 2 + 1];
    ok = m0[0] && m0[1] && m0[2] && m0[3] && m1[0] && m1[1] && m1[2] && m1[3];
  }
  const bool allones = (__syncthreads_and(ok) != 0);

  const int cu = (lane & 7) ^ (lane >> 3);
  const int r0 = wave * 16 + (lane >> 3);
  const u16* kg0 = qkv + (size_t)(b * Sn + r0) * 2304 + 768 + h * 64 + cu * 8;
  const u16* vg0 = vt + (size_t)(bh * 64 + r0) * Sn + cu * 8;
  u16* kd = &kbuf[0][0] + wave * 1024;
  u16* vd = &vbuf[0][0] + wave * 1024;

  const size_t qrowA = (size_t)(b * Sn + qt * 128 + wave * 16 + lr) * 2304 + h * 64 + lg * 8;
  short8 qa0 = *(const short8*)(qkv + qrowA);
  short8 qa1 = *(const short8*)(qkv + qrowA + 32);
  const size_t qrowB = qrowA + (size_t)64 * 2304;
  short8 qb0 = *(const short8*)(qkv + qrowB);
  short8 qb1 = *(const short8*)(qkv + qrowB + 32);

  short8 ones;
#pragma unroll
  for (int j = 0; j < 8; ++j) ones[j] = (short)0x3F80;   // bf16 1.0

  const int rlo = (lg ^ (lr & 7)) << 4;
  const int rhi = ((4 + lg) ^ (lr & 7)) << 4;
  const int rowb = lr * 128;

  f32x4 caccA[4], caccB[4], laccA, laccB;
#pragma unroll
  for (int i = 0; i < 4; ++i) {
    caccA[i] = (f32x4){0.f, 0.f, 0.f, 0.f};
    caccB[i] = (f32x4){0.f, 0.f, 0.f, 0.f};
  }
  laccA = (f32x4){0.f, 0.f, 0.f, 0.f};
  laccB = (f32x4){0.f, 0.f, 0.f, 0.f};

  u16* pwA = &pbuf[wave][0][0];
  u16* pwB = &pbuf[wave][1][0];
  const int pwr = (lg >> 1), pwo = 8 * (lg & 1);

  auto stage = [&](int bf, int c) {
    const u16* kg = kg0 + (size_t)c * 64 * 2304;
    const u16* vg = vg0 + c * 64;
    glds16(kg,            kd + bf * 4096);
    glds16(kg + 8 * 2304, kd + bf * 4096 + 512);
    glds16(vg,            vd + bf * 4096);
    glds16(vg + 8 * Sn,   vd + bf * 4096 + 512);
  };

  stage(0, 0);
  __syncthreads();
  int cur = 0;
  for (int c = 0; c < 32; ++c) {
    if (c + 1 < 32) stage(cur ^ 1, c + 1);
    const char* kb = (const char*)&kbuf[cur][0];
    const char* vb = (const char*)&vbuf[cur][0];

    int4v mk[4];
    if (!allones) {
      const int4v* mp = (const int4v*)(mask + b * Sn + c * 64 + lg * 4);
#pragma unroll
      for (int f = 0; f < 4; ++f) mk[f] = mp[f * 4];
    }

    // QK^T both q-sets, each K fragment read once
    f32x4 scA[4], scB[4];
#pragma unroll
    for (int f = 0; f < 4; ++f) {
      short8 k0 = *(const short8*)(kb + f * 2048 + rowb + rlo);
      short8 k1 = *(const short8*)(kb + f * 2048 + rowb + rhi);
      f32x4 zA = (f32x4){-SHIFT, -SHIFT, -SHIFT, -SHIFT};
      zA = mfma16(k0, qa0, zA);
      zA = mfma16(k1, qa1, zA);
      scA[f] = zA;
      f32x4 zB = (f32x4){-SHIFT, -SHIFT, -SHIFT, -SHIFT};
      zB = mfma16(k0, qb0, zB);
      zB = mfma16(k1, qb1, zB);
      scB[f] = zB;
    }
    if (!allones) {
#pragma unroll
      for (int f = 0; f < 4; ++f)
#pragma unroll
        for (int r = 0; r < 4; ++r) {
          scA[f][r] = mk[f][r] ? scA[f][r] : -1.0e5f;
          scB[f][r] = mk[f][r] ? scB[f][r] : -1.0e5f;
        }
    }
#pragma unroll
    for (int f = 0; f < 4; ++f) {
#pragma unroll
      for (int r = 0; r < 4; ++r) {
        scA[f][r] = exp2_raw(scA[f][r]);
        scB[f][r] = exp2_raw(scB[f][r]);
      }
    }
    // P -> bf16 -> per-wave swizzled LDS (both sets), then read fragments
#pragma unroll
    for (int f = 0; f < 4; ++f) {
      u32x2 wA, wB;
      wA[0] = pk_bf16(scA[f][0], scA[f][1]);
      wA[1] = pk_bf16(scA[f][2], scA[f][3]);
      wB[0] = pk_bf16(scB[f][0], scB[f][1]);
      wB[1] = pk_bf16(scB[f][2], scB[f][3]);
      const int po = rowb + (((2 * f + pwr) ^ (lr & 7)) << 4) + pwo;
      *(u32x2*)((char*)pwA + po) = wA;
      *(u32x2*)((char*)pwB + po) = wB;
    }
    short8 pfA0 = *(const short8*)((const char*)pwA + rowb + rlo);
    short8 pfA1 = *(const short8*)((const char*)pwA + rowb + rhi);
    short8 pfB0 = *(const short8*)((const char*)pwB + rowb + rlo);
    short8 pfB1 = *(const short8*)((const char*)pwB + rowb + rhi);

    // PV both q-sets, each V fragment read once
#pragma unroll
    for (int fd = 0; fd < 4; ++fd) {
      short8 v0 = *(const short8*)(vb + fd * 2048 + rowb + rlo);
      short8 v1 = *(const short8*)(vb + fd * 2048 + rowb + rhi);
      caccA[fd] = mfma16(pfA0, v0, caccA[fd]);
      caccA[fd] = mfma16(pfA1, v1, caccA[fd]);
      caccB[fd] = mfma16(pfB0, v0, caccB[fd]);
      caccB[fd] = mfma16(pfB1, v1, caccB[fd]);
    }
    // l row-sums on the matrix pipe (B = ones)
    laccA = mfma16(pfA0, ones, laccA);
    laccA = mfma16(pfA1, ones, laccA);
    laccB = mfma16(pfB0, ones, laccB);
    laccB = mfma16(pfB1, ones, laccB);
    __syncthreads();
    cur ^= 1;
  }

  float linvA[4], linvB[4];
#pragma unroll
  for (int r = 0; r < 4; ++r) {
    linvA[r] = 1.0f / laccA[r];
    linvB[r] = 1.0f / laccB[r];
  }
  const int orow = b * Sn + qt * 128 + wave * 16 + lg * 4;
#pragma unroll
  for (int fd = 0; fd < 4; ++fd) {
    int col = h * 64 + fd * 16 + lr;
#pragma unroll
    for (int r = 0; r < 4; ++r) {
      ctx[(size_t)(orow + r) * Dn + col] = f2bf(caccA[fd][r] * linvA[r]);
      ctx[(size_t)(orow + 64 + r) * Dn + col] = f2bf(caccB[fd][r] * linvB[r]);
    }
  }
}

// ---- LayerNorm: one wave per row; input = a (+ optional bsrc) --------------
// BSRC: 0 = none (a already contains the residual sum), 1 = fp32, 2 = bf16

template<int BSRC>
__global__ __launch_bounds__(256)
void ln_kernel(const float* __restrict__ a, const void* __restrict__ bsrc,
               const float* __restrict__ alpha, const float* __restrict__ beta,
               float* __restrict__ outf, u16* __restrict__ outb) {
  const int wave = threadIdx.x >> 6, lane = threadIdx.x & 63;
  const size_t base = ((size_t)blockIdx.x * 4 + wave) * Dn;
  const int o = lane * 4;
  f32x4 v[3];
  float s = 0.f, q = 0.f;
#pragma unroll
  for (int j = 0; j < 3; ++j) {
    f32x4 x = *(const f32x4*)(a + base + j * 256 + o);
    if (BSRC == 1) {
      f32x4 bv = *(const f32x4*)((const float*)bsrc + base + j * 256 + o);
      x = x + bv;
    } else if (BSRC == 2) {
      s16x4 bb = *(const s16x4*)((const u16*)bsrc + base + j * 256 + o);
#pragma unroll
      for (int k = 0; k < 4; ++k) x[k] += bf2f((u16)bb[k]);
    }
    v[j] = x;
    s += (x[0] + x[1]) + (x[2] + x[3]);
    q += (x[0] * x[0] + x[1] * x[1]) + (x[2] * x[2] + x[3] * x[3]);
  }
#pragma unroll
  for (int sh = 1; sh < 64; sh <<= 1) {
    s += __shfl_xor(s, sh, 64);
    q += __shfl_xor(q, sh, 64);
  }
  const float mean = s * (1.f / 768.f);
  float var = (q - 768.f * mean * mean) * (1.f / 767.f);
  var = fmaxf(var, 0.f);
  const float rden = 1.f / (sqrtf(var) + EPS);
#pragma unroll
  for (int j = 0; j < 3; ++j) {
    f32x4 al = *(const f32x4*)(alpha + j * 256 + o);
    f32x4 be = *(const f32x4*)(beta + j * 256 + o);
    f32x4 y;
#pragma unroll
    for (int k = 0; k < 4; ++k)
      y[k] = al[k] * (v[j][k] - mean) * rden + be[k];
    if (outf) *(f32x4*)(outf + base + j * 256 + o) = y;
    if (outb) {
      u32x2 w;
      w[0] = pk_bf16(y[0], y[1]);
      w[1] = pk_bf16(y[2], y[3]);
      *(u32x2*)(outb + base + j * 256 + o) = w;
    }
  }
}

// ---------------- launch ----------------

extern "C" void kernel_launch(void* const* d_in, const int* in_sizes, int n_in,
                              void* d_out, int out_size, void* d_ws, size_t ws_size,
                              hipStream_t stream) {
  (void)in_sizes; (void)n_in; (void)out_size; (void)ws_size;
  const float* x    = (const float*)d_in[0];
  const int*   mask = (const int*)d_in[1];
  const float* wq   = (const float*)d_in[2];
  const float* wk   = (const float*)d_in[3];
  const float* wv   = (const float*)d_in[4];
  const float* wo   = (const float*)d_in[5];
  const float* w1   = (const float*)d_in[6];
  const float* b1   = (const float*)d_in[7];
  const float* w2   = (const float*)d_in[8];
  const float* b2   = (const float*)d_in[9];
  const float* ln1a = (const float*)d_in[10];
  const float* ln1b = (const float*)d_in[11];
  const float* ln2a = (const float*)d_in[12];
  const float* ln2b = (const float*)d_in[13];
  float* out = (float*)d_out;

  char* ws = (char*)d_ws;
  size_t off = 0;
  auto alloc = [&](size_t bytes) -> void* {
    void* p = ws + off;
    off += (bytes + 255) & ~(size_t)255;
    return p;
  };
  u16* xb    = (u16*)alloc((size_t)BS * Dn * 2);      // reused as ctx later
  u16* wqkvT = (u16*)alloc((size_t)2304 * Dn * 2);
  u16* woT   = (u16*)alloc((size_t)Dn * Dn * 2);      // contiguous after wqkvT
  u16* w1T   = (u16*)alloc((size_t)DFFn * Dn * 2);
  u16* w2T   = (u16*)alloc((size_t)Dn * DFFn * 2);
  u16* qkv   = (u16*)alloc((size_t)BS * 2304 * 2);
  u16* vt    = (u16*)alloc((size_t)48 * 64 * Sn * 2);
  u16* x1b   = (u16*)alloc((size_t)BS * Dn * 2);
  u16* ff1   = (u16*)alloc((size_t)BS * DFFn * 2);
  u16* ctx   = xb;
  (void)woT;

  dim3 blk256(256), blk512(512);
  // fused prep: x conversion + all weight transposes (wqkvT[0..3] incl. woT)
  prep_kernel<<<dim3(9984), blk256, 0, stream>>>(x, wq, wk, wv, wo, w1, w2,
                                                 xb, wqkvT, w1T, w2T);

  // qkv = xb @ [wq'|wk|wv]; V tiles fused-transposed into vt
  gemm_kernel<256, true, false, false, true, 0><<<dim3(576), blk512, 0, stream>>>(xb, wqkvT, nullptr, qkv, 2304, 768, 18, vt, nullptr);
  attn_kernel<<<dim3(768), blk256, 0, stream>>>(qkv, vt, mask, ctx);
  // out = ctx @ wo + x   (residual fused)
  gemm_kernel<128, false, false, false, false, 1><<<dim3(384), blk256, 0, stream>>>(ctx, wqkvT + 3 * Dn * Dn, nullptr, out, 768, 768, 6, nullptr, x);
  // x1 = LN(out) -> bf16
  ln_kernel<0><<<dim3(BS / 4), blk256, 0, stream>>>(out, nullptr, ln1a, ln1b, nullptr, x1b);
  // ff1 = relu(x1 @ w1 + b1)
  gemm_kernel<256, true, true, true, false, 0><<<dim3(768), blk512, 0, stream>>>(x1b, w1T, b1, ff1, 3072, 768, 24, nullptr, nullptr);
  // out = ff1 @ w2 + b2 + x1   (residual fused)
  gemm_kernel<128, false, false, true, false, 2><<<dim3(384), blk256, 0, stream>>>(ff1, w2T, b2, out, 768, 3072, 6, nullptr, x1b);
  // out = LN(out)
  ln_kernel<0><<<dim3(BS / 4), blk256, 0, stream>>>(out, nullptr, ln2a, ln2b, out, nullptr);
}